// Round 7
// baseline (329.726 us; speedup 1.0000x reference)
//
#include <hip/hip_runtime.h>

#define NNODES 50000
#define NEDGES 800000
#define NCLASS 40
#define CNTB  3125      // NEDGES/256
#define PREPB 320       // 5*16384/256
#define WOUTB 24        // 48*128/256
#define GEMMB 782       // ceil(NNODES/64)
#define XBLK  3125      // NNODES/16, 16 nodes per 128-thread layer block
#define WELL  64        // ELL width (Poisson(16) max degree ~45; 64 = huge margin)
#define CPAD  16        // counter padding: 1 counter per 64B sector kills atomic line contention

typedef _Float16 half8  __attribute__((ext_vector_type(8)));
typedef float    floatx4 __attribute__((ext_vector_type(4)));

// Cs transpose buffer for the 64-row fp32-A gemm: 64 rows x 136 halfs + 64 floats of dinv
#define CSTR 136
#define SMEM_BYTES (64 * CSTR * 2 + 256)

__device__ __forceinline__ float fast_tanh(float x) {
    return 1.0f - 2.0f / (__expf(2.0f * x) + 1.0f);
}

// ---------------- fused pre-pass: count + DIRECT ELL scatter | weights -> MFMA-frag order ----------
// ELL kills the separate CSR fill pass and the scan: slot = atomicAdd(cnt[dst]) IS the position.
// Counters padded to 64B sectors: ~16 contending atomics per line (one node) instead of ~512.
// Fragment layout (per 128x128 mat): element (n = ct*16 + l15, k = kk*32 + quad*8 + j)
// stored at ((kk*8 + ct)*64 + quad*16 + l15)*8 + j.
__global__ __launch_bounds__(256) void k_pre(const int* __restrict__ src, const int* __restrict__ dst,
                                             int* __restrict__ cnt, int* __restrict__ esrc,
                                             const float* __restrict__ convW, const float* __restrict__ W_att,
                                             _Float16* __restrict__ WT,
                                             const float* __restrict__ Wout, _Float16* __restrict__ WoutT) {
    int bid = blockIdx.x, tid = threadIdx.x;
    if (bid < CNTB) {
        int e = bid * 256 + tid;
        int d = dst[e];
        int slot = atomicAdd(&cnt[d * CPAD], 1);
        esrc[d * WELL + slot] = src[e];
    } else if (bid < CNTB + PREPB) {
        int idx = (bid - CNTB) * 256 + tid;   // < 5*16384
        int mat = idx >> 14, rem = idx & 16383;
        int j = rem & 7, lane = (rem >> 3) & 63, tile = rem >> 9;
        int l15 = lane & 15, quad = lane >> 4;
        int ct = tile & 7, kk = tile >> 3;
        int n = ct * 16 + l15, k = kk * 32 + quad * 8 + j;
        const float* s = (mat < 4) ? (convW + mat * 16384) : W_att;
        WT[idx] = (_Float16)s[k * 128 + n];
    } else {
        int idx = (bid - CNTB - PREPB) * 256 + tid;   // < 12*512 = 6144
        int j = idx & 7, lane = (idx >> 3) & 63, tile = idx >> 9;
        int l15 = lane & 15, quad = lane >> 4;
        int ct = tile % 3, kk = tile / 3;
        int n = ct * 16 + l15, k = kk * 32 + quad * 8 + j;
        WoutT[idx] = (n < NCLASS) ? (_Float16)Wout[k * NCLASS + n] : (_Float16)0.f;
    }
}

// ---------------- 64-row GEMM (layer-0 only, fp32 A): C = (A @ W) * dinv; dinv from cnt ------------
__global__ __launch_bounds__(256) void k_gemm0(const float* __restrict__ Av, const _Float16* __restrict__ WTf,
                                               const int* __restrict__ cnt, _Float16* __restrict__ C) {
    __shared__ __align__(16) char smem[SMEM_BYTES];
    _Float16 (*Csh)[CSTR] = (_Float16 (*)[CSTR])smem;
    float* sdinv = (float*)(smem + 64 * CSTR * 2);
    int m0 = blockIdx.x * 64;
    int tid = threadIdx.x;
    int wave = tid >> 6, lane = tid & 63;
    int quad = lane >> 4, l15 = lane & 15;
    int ko = quad * 8;

    if (tid < 64) {
        int r = m0 + tid; if (r > NNODES - 1) r = NNODES - 1;
        sdinv[tid] = rsqrtf((float)cnt[r * CPAD] + 1.0f);
    }

    floatx4 acc[4][2];
#pragma unroll
    for (int rt = 0; rt < 4; ++rt)
#pragma unroll
        for (int ct = 0; ct < 2; ++ct) acc[rt][ct] = (floatx4){0.f, 0.f, 0.f, 0.f};

#pragma unroll
    for (int kk = 0; kk < 4; ++kk) {
        half8 a[4], b[2];
#pragma unroll
        for (int rt = 0; rt < 4; ++rt) {
            int row = m0 + rt * 16 + l15;
            if (row > NNODES - 1) row = NNODES - 1;
            const float* Ap = Av + (size_t)row * 128 + kk * 32 + ko;
            float4 f0 = *(const float4*)Ap;
            float4 f1 = *(const float4*)(Ap + 4);
            a[rt] = (half8){(_Float16)f0.x, (_Float16)f0.y, (_Float16)f0.z, (_Float16)f0.w,
                            (_Float16)f1.x, (_Float16)f1.y, (_Float16)f1.z, (_Float16)f1.w};
        }
#pragma unroll
        for (int ct = 0; ct < 2; ++ct)
            b[ct] = *(const half8*)&WTf[((kk * 8 + (wave * 2 + ct)) * 64 + lane) * 8];
#pragma unroll
        for (int rt = 0; rt < 4; ++rt)
#pragma unroll
            for (int ct = 0; ct < 2; ++ct)
                acc[rt][ct] = __builtin_amdgcn_mfma_f32_16x16x32_f16(a[rt], b[ct], acc[rt][ct], 0, 0, 0);
    }
    __syncthreads();   // sdinv visible

#pragma unroll
    for (int rt = 0; rt < 4; ++rt)
#pragma unroll
        for (int r = 0; r < 4; ++r) {
            float d = sdinv[rt * 16 + quad * 4 + r];
#pragma unroll
            for (int ct = 0; ct < 2; ++ct)
                Csh[rt * 16 + quad * 4 + r][wave * 32 + ct * 16 + l15] = (_Float16)(acc[rt][ct][r] * d);
        }
    __syncthreads();

    int row = tid >> 2, seg = tid & 3;
    int gm = m0 + row;
    if (gm < NNODES) {
#pragma unroll
        for (int j = 0; j < 4; ++j)
            *(half8*)(C + (size_t)gm * 128 + seg * 32 + j * 8) = *(const half8*)&Csh[row][seg * 32 + j * 8];
    }
}

// ---------------- fused layer kernel: aggregate(l) | attention(l) | gemm(l+1) ----------------
// Block = 128 threads (2 waves), 16 nodes. Aggregation: 8 lanes/node, 4-deep pipelined gathers.
// ELL edge list: beg = n*WELL, end = beg + cnt[n] -> no offsets array, no dinv array.
// Post-relu h kept in LDS -> attention and next-layer GEMM read it from LDS (no global re-read).
// Gathers read hin; gemm writes hout (ping-pong buffers, so no intra-kernel race).
template <bool HAS_GEMM>
__global__ __launch_bounds__(128) void k_layer(const _Float16* __restrict__ hin,
                                               const int* __restrict__ cnt, const int* __restrict__ esrc,
                                               const float* __restrict__ bias,
                                               _Float16* __restrict__ hh,
                                               const _Float16* __restrict__ WTatt, const float* __restrict__ a_att,
                                               float* __restrict__ scores, int layer,
                                               const _Float16* __restrict__ WTnext, _Float16* __restrict__ hout) {
    __shared__ __align__(16) _Float16 h[16][CSTR];   // 4,352 B; reused as Cs in the gemm epilogue
    __shared__ float bsh[128];
    __shared__ float sdv[16];
    __shared__ float pp[2][16];
    int tid = threadIdx.x;
    bsh[tid] = bias[tid];
    int wave = tid >> 6, lane = tid & 63;
    int n0 = blockIdx.x * 16;

    // ---- P1: aggregate 16 nodes (8 lanes per node, 16 channels per lane) ----
    {
        int nl = tid >> 3;               // 0..15
        int cl = tid & 7;
        int c16 = cl * 16;
        int n = n0 + nl;                 // XBLK*16 == NNODES: always valid
        int cv = cnt[n * CPAD];
        int beg = n * WELL, end = beg + cv;
        float dn = rsqrtf((float)cv + 1.0f);
        const _Float16* sp = hin + (size_t)n * 128 + c16;
        half8 sv0 = *(const half8*)sp;
        half8 sv1 = *(const half8*)(sp + 8);

        float a[16];
#pragma unroll
        for (int u = 0; u < 16; ++u) a[u] = 0.f;

        int idxA[4]; float mskA[4];
#pragma unroll
        for (int i = 0; i < 4; ++i) {
            int ei = beg + i;
            int t = esrc[ei];            // esrc padded: speculative load in-bounds
            bool ok = ei < end;
            idxA[i] = ok ? t : n;
            mskA[i] = ok ? 1.f : 0.f;
        }
        for (int e = beg; e < end; e += 4) {
            half8 v0[4], v1[4];
#pragma unroll
            for (int i = 0; i < 4; ++i) {
                const _Float16* p = hin + (size_t)idxA[i] * 128 + c16;
                v0[i] = *(const half8*)p;
                v1[i] = *(const half8*)(p + 8);
            }
            int idxB[4]; float mskB[4];
#pragma unroll
            for (int i = 0; i < 4; ++i) {
                int ei = e + 4 + i;
                int t = esrc[ei];        // padded: always in-bounds
                bool ok = ei < end;
                idxB[i] = ok ? t : n;
                mskB[i] = ok ? 1.f : 0.f;
            }
#pragma unroll
            for (int i = 0; i < 4; ++i) {
                float m = mskA[i];
#pragma unroll
                for (int u = 0; u < 8; ++u) {
                    a[u]     += m * (float)v0[i][u];
                    a[8 + u] += m * (float)v1[i][u];
                }
            }
#pragma unroll
            for (int i = 0; i < 4; ++i) { idxA[i] = idxB[i]; mskA[i] = mskB[i]; }
        }
        __syncthreads();   // bsh ready
        half8 o0, o1;
#pragma unroll
        for (int u = 0; u < 8; ++u) {
            float r0 = (a[u]     + (float)sv0[u]) * dn + bsh[c16 + u];
            float r1 = (a[8 + u] + (float)sv1[u]) * dn + bsh[c16 + 8 + u];
            o0[u] = (_Float16)fmaxf(r0, 0.f);
            o1[u] = (_Float16)fmaxf(r1, 0.f);
        }
        *(half8*)(hh + (size_t)n * 128 + c16)     = o0;
        *(half8*)(hh + (size_t)n * 128 + c16 + 8) = o1;
        *(half8*)&h[nl][c16]     = o0;
        *(half8*)&h[nl][c16 + 8] = o1;
        if (cl == 0) sdv[nl] = dn;
    }
    __syncthreads();

    int quad = lane >> 4, l15 = lane & 15;
    int ko = quad * 8;
    half8 af[4];                          // A-frags of the 16 rows, shared by attn + gemm
#pragma unroll
    for (int kk = 0; kk < 4; ++kk) af[kk] = *(const half8*)&h[l15][kk * 32 + ko];

    // ---- P2: attention scores for these 16 nodes (wave w handles cols w*64..w*64+63) ----
    {
        float p[4] = {0.f, 0.f, 0.f, 0.f};
#pragma unroll
        for (int c2 = 0; c2 < 4; ++c2) {
            int ct = wave * 4 + c2;
            half8 b[4];
#pragma unroll
            for (int kk = 0; kk < 4; ++kk)
                b[kk] = *(const half8*)&WTatt[((kk * 8 + ct) * 64 + lane) * 8];
            floatx4 acc = (floatx4){0.f, 0.f, 0.f, 0.f};
#pragma unroll
            for (int kk = 0; kk < 4; ++kk)
                acc = __builtin_amdgcn_mfma_f32_16x16x32_f16(af[kk], b[kk], acc, 0, 0, 0);
            float av = a_att[ct * 16 + l15];
#pragma unroll
            for (int r = 0; r < 4; ++r) p[r] += av * fast_tanh(acc[r]);
        }
#pragma unroll
        for (int r = 0; r < 4; ++r) {
            float v = p[r];
            v += __shfl_xor(v, 1); v += __shfl_xor(v, 2);
            v += __shfl_xor(v, 4); v += __shfl_xor(v, 8);
            if (l15 == 0) pp[wave][quad * 4 + r] = v;
        }
    }
    __syncthreads();
    if (tid < 16) scores[(size_t)(n0 + tid) * 4 + layer] = pp[0][tid] + pp[1][tid];

    // ---- P3: next-layer GEMM, A from LDS ----
    if (HAS_GEMM) {
        floatx4 acc[4];
#pragma unroll
        for (int c2 = 0; c2 < 4; ++c2) acc[c2] = (floatx4){0.f, 0.f, 0.f, 0.f};
#pragma unroll
        for (int c2 = 0; c2 < 4; ++c2) {
            int ct = wave * 4 + c2;
#pragma unroll
            for (int kk = 0; kk < 4; ++kk) {
                half8 b = *(const half8*)&WTnext[((kk * 8 + ct) * 64 + lane) * 8];
                acc[c2] = __builtin_amdgcn_mfma_f32_16x16x32_f16(af[kk], b, acc[c2], 0, 0, 0);
            }
        }
        __syncthreads();   // everyone done reading h before it becomes Cs
#pragma unroll
        for (int c2 = 0; c2 < 4; ++c2) {
            int col = wave * 64 + c2 * 16 + l15;
#pragma unroll
            for (int r = 0; r < 4; ++r) {
                int row = quad * 4 + r;
                h[row][col] = (_Float16)(acc[c2][r] * sdv[row]);
            }
        }
        __syncthreads();
        int row = tid >> 3, seg = tid & 7;
        int gm = n0 + row;
        *(half8*)(hout + (size_t)gm * 128 + seg * 16)     = *(const half8*)&h[row][seg * 16];
        *(half8*)(hout + (size_t)gm * 128 + seg * 16 + 8) = *(const half8*)&h[row][seg * 16 + 8];
    }
}

// ---------------- softmax + layer-fuse (coalesced, all lanes) + MFMA out-projection ----------------
__global__ __launch_bounds__(256) void k_fuse_out(const _Float16* __restrict__ hbase, const float* __restrict__ scores,
                                                  const _Float16* __restrict__ WoutT, const float* __restrict__ bout,
                                                  float* __restrict__ out) {
    __shared__ __align__(16) _Float16 Fs[64][136];   // 17,408 B
    __shared__ float salpha[256];
    const size_t LSTR = (size_t)NNODES * 128;
    int tid = threadIdx.x;
    int n0 = blockIdx.x * 64;

    if (tid < 64) {
        int node = n0 + tid; if (node > NNODES - 1) node = NNODES - 1;
        float4 s = *(const float4*)(scores + (size_t)node * 4);
        float mx = fmaxf(fmaxf(s.x, s.y), fmaxf(s.z, s.w));
        float e0 = __expf(s.x - mx), e1 = __expf(s.y - mx), e2 = __expf(s.z - mx), e3 = __expf(s.w - mx);
        float inv = 1.0f / (e0 + e1 + e2 + e3);
        salpha[tid * 4 + 0] = e0 * inv; salpha[tid * 4 + 1] = e1 * inv;
        salpha[tid * 4 + 2] = e2 * inv; salpha[tid * 4 + 3] = e3 * inv;
    }
    __syncthreads();

    // fused = sum_l alpha_l * h_l; all 256 lanes, coalesced per (layer, j)
    {
        int no = tid >> 2, seg = tid & 3;
        int node = n0 + no; if (node > NNODES - 1) node = NNODES - 1;
        float al0 = salpha[no * 4 + 0], al1 = salpha[no * 4 + 1];
        float al2 = salpha[no * 4 + 2], al3 = salpha[no * 4 + 3];
        const _Float16* hp = hbase + (size_t)node * 128 + seg * 32;
#pragma unroll
        for (int j = 0; j < 4; ++j) {
            half8 h0 = *(const half8*)(hp + 0 * LSTR + j * 8);
            half8 h1 = *(const half8*)(hp + 1 * LSTR + j * 8);
            half8 h2 = *(const half8*)(hp + 2 * LSTR + j * 8);
            half8 h3 = *(const half8*)(hp + 3 * LSTR + j * 8);
            half8 f;
#pragma unroll
            for (int u = 0; u < 8; ++u)
                f[u] = (_Float16)(al0 * (float)h0[u] + al1 * (float)h1[u] +
                                  al2 * (float)h2[u] + al3 * (float)h3[u]);
            *(half8*)&Fs[no][seg * 32 + j * 8] = f;
        }
    }
    __syncthreads();

    // out-projection MFMA: 48 padded cols (3 frag tiles), masked fp32 write + bias
    int wave = tid >> 6, lane = tid & 63;
    int quad = lane >> 4, l15 = lane & 15;
    int ko = quad * 8;
    half8 ff[4];
    int frow = wave * 16 + l15;
#pragma unroll
    for (int kk = 0; kk < 4; ++kk) ff[kk] = *(const half8*)&Fs[frow][kk * 32 + ko];
#pragma unroll
    for (int ct = 0; ct < 3; ++ct) {
        half8 bw[4];
#pragma unroll
        for (int kk = 0; kk < 4; ++kk)
            bw[kk] = *(const half8*)(WoutT + ((kk * 3 + ct) * 64 + lane) * 8);
        floatx4 acc = (floatx4){0.f, 0.f, 0.f, 0.f};
#pragma unroll
        for (int kk = 0; kk < 4; ++kk)
            acc = __builtin_amdgcn_mfma_f32_16x16x32_f16(ff[kk], bw[kk], acc, 0, 0, 0);
        int col = ct * 16 + l15;
        if (col < NCLASS) {
            float bv = bout[col];
#pragma unroll
            for (int r = 0; r < 4; ++r) {
                int node = n0 + wave * 16 + quad * 4 + r;
                if (node < NNODES) out[(size_t)node * NCLASS + col] = acc[r] + bv;
            }
        }
    }
}

extern "C" void kernel_launch(void* const* d_in, const int* in_sizes, int n_in,
                              void* d_out, int out_size, void* d_ws, size_t ws_size,
                              hipStream_t stream) {
    const float* x     = (const float*)d_in[0];
    const int*   ei    = (const int*)d_in[1];
    const float* convW = (const float*)d_in[2];
    const float* convb = (const float*)d_in[3];
    const float* W_att = (const float*)d_in[4];
    const float* a_att = (const float*)d_in[5];
    const float* W_out = (const float*)d_in[6];
    const float* b_out = (const float*)d_in[7];
    float* out = (float*)d_out;

    char* ws = (char*)d_ws;
    size_t off = 0;
    auto take = [&](size_t nbytes) { char* p = ws + off; off += (nbytes + 255) & ~(size_t)255; return p; };
    int*       cnt     = (int*)take((size_t)NNODES * CPAD * 4);          // padded: 1 counter / 64B
    int*       esrc    = (int*)take((size_t)NNODES * WELL * 4 + 1024);   // ELL + pad for speculative loads
    _Float16*  WoutT   = (_Float16*)take((size_t)48 * 128 * 2);
    float*     scores  = (float*)take(NNODES * 4 * 4);
    _Float16*  WT      = (_Float16*)take((size_t)5 * 128 * 128 * 2);
    _Float16*  hWsA    = (_Float16*)take((size_t)NNODES * 128 * 2);
    _Float16*  hh[4];
    for (int l = 0; l < 4; ++l) hh[l] = (_Float16*)take((size_t)NNODES * 128 * 2);
    // NOTE: hh slabs are 12,800,000 B each (multiple of 256) -> contiguous; k_fuse_out relies on it.
    _Float16*  hWsB    = (_Float16*)take((size_t)NNODES * 128 * 2);

    const int* src = ei;
    const int* dst = ei + NEDGES;

    hipMemsetAsync(cnt, 0, (size_t)NNODES * CPAD * 4, stream);
    k_pre<<<CNTB + PREPB + WOUTB, 256, 0, stream>>>(src, dst, cnt, esrc, convW, W_att, WT, W_out, WoutT);
    k_gemm0<<<GEMMB, 256, 0, stream>>>(x, WT, cnt, hWsA);

    // layer kernels: aggregate(l) + attention(l) + gemm(l+1); hWs ping-pongs A->B->A->B
    k_layer<true><<<XBLK, 128, 0, stream>>>(hWsA, cnt, esrc, convb + 0 * 128, hh[0],
                                            WT + 4 * 16384, a_att, scores, 0, WT + 1 * 16384, hWsB);
    k_layer<true><<<XBLK, 128, 0, stream>>>(hWsB, cnt, esrc, convb + 1 * 128, hh[1],
                                            WT + 4 * 16384, a_att, scores, 1, WT + 2 * 16384, hWsA);
    k_layer<true><<<XBLK, 128, 0, stream>>>(hWsA, cnt, esrc, convb + 2 * 128, hh[2],
                                            WT + 4 * 16384, a_att, scores, 2, WT + 3 * 16384, hWsB);
    k_layer<false><<<XBLK, 128, 0, stream>>>(hWsB, cnt, esrc, convb + 3 * 128, hh[3],
                                             WT + 4 * 16384, a_att, scores, 3, (const _Float16*)nullptr,
                                             (_Float16*)nullptr);
    k_fuse_out<<<GEMMB, 256, 0, stream>>>(hh[0], scores, WoutT, b_out, out);
}

// Round 8
// 303.374 us; speedup vs baseline: 1.0869x; 1.0869x over previous
//
#include <hip/hip_runtime.h>

#define NNODES 50000
#define NEDGES 800000
#define NCLASS 40
#define GEMMB 782      // ceil(NNODES/64)
#define XBLK  3125     // NNODES/16, 16 nodes per 128-thread layer block
#define WELL  64       // ELL width (Poisson(16) max degree ~45; 64 = huge margin)

// ---- edge-partition geometry ----
#define EBLK  782      // edge blocks of 1024 threads (800K edges)
#define PREPB 80       // 5*16384/1024 weight-prep blocks
#define WOUTB 6        // 6144/1024 WoutT-prep blocks
#define BSHIFT 10
#define NB    49       // ceil(50000/1024) coarse buckets
#define NCNT  (NB * EBLK)        // 38,318 (bucket-major)
#define SCANB 38       // ceil(NCNT/1024)

typedef _Float16 half8  __attribute__((ext_vector_type(8)));
typedef float    floatx4 __attribute__((ext_vector_type(4)));

#define CSTR 136
#define SMEM_BYTES (64 * CSTR * 2 + 256)

__device__ __forceinline__ float fast_tanh(float x) {
    return 1.0f - 2.0f / (__expf(2.0f * x) + 1.0f);
}

// ---------------- phase A: per-block bucket histogram | weight prep (frag order) ----------------
__global__ __launch_bounds__(1024) void k_hist(const int* __restrict__ dst, int* __restrict__ counts,
                                               const float* __restrict__ convW, const float* __restrict__ W_att,
                                               _Float16* __restrict__ WT,
                                               const float* __restrict__ Wout, _Float16* __restrict__ WoutT) {
    int bid = blockIdx.x, tid = threadIdx.x;
    if (bid < EBLK) {
        __shared__ int hist[NB];
        if (tid < NB) hist[tid] = 0;
        __syncthreads();
        int e = bid * 1024 + tid;
        if (e < NEDGES) atomicAdd(&hist[dst[e] >> BSHIFT], 1);
        __syncthreads();
        if (tid < NB) counts[tid * EBLK + bid] = hist[tid];
    } else if (bid < EBLK + PREPB) {
        int idx = (bid - EBLK) * 1024 + tid;   // < 5*16384
        int mat = idx >> 14, rem = idx & 16383;
        int j = rem & 7, lane = (rem >> 3) & 63, tile = rem >> 9;
        int l15 = lane & 15, quad = lane >> 4;
        int ct = tile & 7, kk = tile >> 3;
        int n = ct * 16 + l15, k = kk * 32 + quad * 8 + j;
        const float* s = (mat < 4) ? (convW + mat * 16384) : W_att;
        WT[idx] = (_Float16)s[k * 128 + n];
    } else {
        int idx = (bid - EBLK - PREPB) * 1024 + tid;   // < 6144
        int j = idx & 7, lane = (idx >> 3) & 63, tile = idx >> 9;
        int l15 = lane & 15, quad = lane >> 4;
        int ct = tile % 3, kk = tile / 3;
        int n = ct * 16 + l15, k = kk * 32 + quad * 8 + j;
        WoutT[idx] = (n < NCLASS) ? (_Float16)Wout[k * NCLASS + n] : (_Float16)0.f;
    }
}

// ---------------- phase B1: per-1024-tile sums of counts ----------------
__global__ __launch_bounds__(1024) void k_bsum(const int* __restrict__ counts, int* __restrict__ bsum) {
    int t = threadIdx.x, b = blockIdx.x;
    int i = b * 1024 + t;
    int v = (i < NCNT) ? counts[i] : 0;
    v += __shfl_xor(v, 1);  v += __shfl_xor(v, 2);  v += __shfl_xor(v, 4);
    v += __shfl_xor(v, 8);  v += __shfl_xor(v, 16); v += __shfl_xor(v, 32);
    __shared__ int ws[16];
    if ((t & 63) == 0) ws[t >> 6] = v;
    __syncthreads();
    if (t == 0) {
        int s = 0;
#pragma unroll
        for (int w = 0; w < 16; ++w) s += ws[w];
        bsum[b] = s;
    }
}

// ---------------- phase B2: exclusive scan of counts (in place) ----------------
__global__ __launch_bounds__(1024) void k_scan(int* __restrict__ counts, const int* __restrict__ bsum) {
    __shared__ int part[1024];
    __shared__ int ws[16];
    int t = threadIdx.x, b = blockIdx.x;
    int i = b * 1024 + t;
    int c = (i < NCNT) ? counts[i] : 0;
    // sum of previous tiles
    int pv = (t < b) ? bsum[t] : 0;    // b <= 37 < 1024
    pv += __shfl_xor(pv, 1);  pv += __shfl_xor(pv, 2);  pv += __shfl_xor(pv, 4);
    pv += __shfl_xor(pv, 8);  pv += __shfl_xor(pv, 16); pv += __shfl_xor(pv, 32);
    if ((t & 63) == 0) ws[t >> 6] = pv;
    part[t] = c;
    __syncthreads();
    int boff = 0;
#pragma unroll
    for (int w = 0; w < 16; ++w) boff += ws[w];
    // inclusive scan of the tile
#pragma unroll
    for (int d = 1; d < 1024; d <<= 1) {
        int v = (t >= d) ? part[t - d] : 0;
        __syncthreads();
        part[t] += v;
        __syncthreads();
    }
    if (i < NCNT) counts[i] = boff + part[t] - c;   // exclusive base
}

// ---------------- phase C: partition edges into bucket-major (src,dst) pairs ----------------
// Per (block,bucket) ~21 edges -> ~168B contiguous runs: near-streaming writes.
__global__ __launch_bounds__(1024) void k_part(const int* __restrict__ src, const int* __restrict__ dst,
                                               const int* __restrict__ counts, int2* __restrict__ ebuf) {
    __shared__ int hist2[NB];
    int bid = blockIdx.x, tid = threadIdx.x;
    if (tid < NB) hist2[tid] = 0;
    __syncthreads();
    int e = bid * 1024 + tid;
    if (e < NEDGES) {
        int d = dst[e];
        int s = src[e];
        int b = d >> BSHIFT;
        int slot = atomicAdd(&hist2[b], 1);
        int pos = counts[b * EBLK + bid] + slot;
        ebuf[pos] = make_int2(s, d);
    }
}

// ---------------- phase D: per-bucket ELL build; esrc writes land in a 256KB L2-resident window ----
__global__ __launch_bounds__(1024) void k_build(const int* __restrict__ counts, const int2* __restrict__ ebuf,
                                                int* __restrict__ esrc, int* __restrict__ cnt) {
    __shared__ int lcnt[1024];
    int b = blockIdx.x, t = threadIdx.x;
    lcnt[t] = 0;
    __syncthreads();
    int n0 = b << BSHIFT;
    int lo = counts[b * EBLK];
    int hi = (b < NB - 1) ? counts[(b + 1) * EBLK] : NEDGES;
    for (int i = lo + t; i < hi; i += 1024) {
        int2 p = ebuf[i];
        int slot = atomicAdd(&lcnt[p.y - n0], 1);
        esrc[p.y * WELL + slot] = p.x;
    }
    __syncthreads();
    int n = n0 + t;
    if (n < NNODES) cnt[n] = lcnt[t];
}

// ---------------- 64-row GEMM (layer-0 only, fp32 A): C = (A @ W) * dinv; dinv from cnt ------------
__global__ __launch_bounds__(256) void k_gemm0(const float* __restrict__ Av, const _Float16* __restrict__ WTf,
                                               const int* __restrict__ cnt, _Float16* __restrict__ C) {
    __shared__ __align__(16) char smem[SMEM_BYTES];
    _Float16 (*Csh)[CSTR] = (_Float16 (*)[CSTR])smem;
    float* sdinv = (float*)(smem + 64 * CSTR * 2);
    int m0 = blockIdx.x * 64;
    int tid = threadIdx.x;
    int wave = tid >> 6, lane = tid & 63;
    int quad = lane >> 4, l15 = lane & 15;
    int ko = quad * 8;

    if (tid < 64) {
        int r = m0 + tid; if (r > NNODES - 1) r = NNODES - 1;
        sdinv[tid] = rsqrtf((float)cnt[r] + 1.0f);
    }

    floatx4 acc[4][2];
#pragma unroll
    for (int rt = 0; rt < 4; ++rt)
#pragma unroll
        for (int ct = 0; ct < 2; ++ct) acc[rt][ct] = (floatx4){0.f, 0.f, 0.f, 0.f};

#pragma unroll
    for (int kk = 0; kk < 4; ++kk) {
        half8 a[4], b[2];
#pragma unroll
        for (int rt = 0; rt < 4; ++rt) {
            int row = m0 + rt * 16 + l15;
            if (row > NNODES - 1) row = NNODES - 1;
            const float* Ap = Av + (size_t)row * 128 + kk * 32 + ko;
            float4 f0 = *(const float4*)Ap;
            float4 f1 = *(const float4*)(Ap + 4);
            a[rt] = (half8){(_Float16)f0.x, (_Float16)f0.y, (_Float16)f0.z, (_Float16)f0.w,
                            (_Float16)f1.x, (_Float16)f1.y, (_Float16)f1.z, (_Float16)f1.w};
        }
#pragma unroll
        for (int ct = 0; ct < 2; ++ct)
            b[ct] = *(const half8*)&WTf[((kk * 8 + (wave * 2 + ct)) * 64 + lane) * 8];
#pragma unroll
        for (int rt = 0; rt < 4; ++rt)
#pragma unroll
            for (int ct = 0; ct < 2; ++ct)
                acc[rt][ct] = __builtin_amdgcn_mfma_f32_16x16x32_f16(a[rt], b[ct], acc[rt][ct], 0, 0, 0);
    }
    __syncthreads();   // sdinv visible

#pragma unroll
    for (int rt = 0; rt < 4; ++rt)
#pragma unroll
        for (int r = 0; r < 4; ++r) {
            float d = sdinv[rt * 16 + quad * 4 + r];
#pragma unroll
            for (int ct = 0; ct < 2; ++ct)
                Csh[rt * 16 + quad * 4 + r][wave * 32 + ct * 16 + l15] = (_Float16)(acc[rt][ct][r] * d);
        }
    __syncthreads();

    int row = tid >> 2, seg = tid & 3;
    int gm = m0 + row;
    if (gm < NNODES) {
#pragma unroll
        for (int j = 0; j < 4; ++j)
            *(half8*)(C + (size_t)gm * 128 + seg * 32 + j * 8) = *(const half8*)&Csh[row][seg * 32 + j * 8];
    }
}

// ---------------- fused layer kernel: aggregate(l) | attention(l) | gemm(l+1) ----------------
// Block = 128 threads (2 waves), 16 nodes. Aggregation: 8 lanes/node, 4-deep pipelined gathers.
// ELL edge list: beg = n*WELL, end = beg + cnt[n]. Post-relu h kept in LDS -> attention and
// next-layer GEMM read it from LDS. Gathers read hin; gemm writes hout (ping-pong, no race).
template <bool HAS_GEMM>
__global__ __launch_bounds__(128) void k_layer(const _Float16* __restrict__ hin,
                                               const int* __restrict__ cnt, const int* __restrict__ esrc,
                                               const float* __restrict__ bias,
                                               _Float16* __restrict__ hh,
                                               const _Float16* __restrict__ WTatt, const float* __restrict__ a_att,
                                               float* __restrict__ scores, int layer,
                                               const _Float16* __restrict__ WTnext, _Float16* __restrict__ hout) {
    __shared__ __align__(16) _Float16 h[16][CSTR];   // 4,352 B; reused as Cs in the gemm epilogue
    __shared__ float bsh[128];
    __shared__ float sdv[16];
    __shared__ float pp[2][16];
    int tid = threadIdx.x;
    bsh[tid] = bias[tid];
    int wave = tid >> 6, lane = tid & 63;
    int n0 = blockIdx.x * 16;

    // ---- P1: aggregate 16 nodes (8 lanes per node, 16 channels per lane) ----
    {
        int nl = tid >> 3;               // 0..15
        int cl = tid & 7;
        int c16 = cl * 16;
        int n = n0 + nl;                 // XBLK*16 == NNODES: always valid
        int cv = cnt[n];
        int beg = n * WELL, end = beg + cv;
        float dn = rsqrtf((float)cv + 1.0f);
        const _Float16* sp = hin + (size_t)n * 128 + c16;
        half8 sv0 = *(const half8*)sp;
        half8 sv1 = *(const half8*)(sp + 8);

        float a[16];
#pragma unroll
        for (int u = 0; u < 16; ++u) a[u] = 0.f;

        int idxA[4]; float mskA[4];
#pragma unroll
        for (int i = 0; i < 4; ++i) {
            int ei = beg + i;
            int t = esrc[ei];            // within the 64-slot row: always in-bounds
            bool ok = ei < end;
            idxA[i] = ok ? t : n;
            mskA[i] = ok ? 1.f : 0.f;
        }
        for (int e = beg; e < end; e += 4) {
            half8 v0[4], v1[4];
#pragma unroll
            for (int i = 0; i < 4; ++i) {
                const _Float16* p = hin + (size_t)idxA[i] * 128 + c16;
                v0[i] = *(const half8*)p;
                v1[i] = *(const half8*)(p + 8);
            }
            int idxB[4]; float mskB[4];
#pragma unroll
            for (int i = 0; i < 4; ++i) {
                int ei = e + 4 + i;
                int t = esrc[ei];        // within row (cv+8 <= 53 < 64)
                bool ok = ei < end;
                idxB[i] = ok ? t : n;
                mskB[i] = ok ? 1.f : 0.f;
            }
#pragma unroll
            for (int i = 0; i < 4; ++i) {
                float m = mskA[i];
#pragma unroll
                for (int u = 0; u < 8; ++u) {
                    a[u]     += m * (float)v0[i][u];
                    a[8 + u] += m * (float)v1[i][u];
                }
            }
#pragma unroll
            for (int i = 0; i < 4; ++i) { idxA[i] = idxB[i]; mskA[i] = mskB[i]; }
        }
        __syncthreads();   // bsh ready
        half8 o0, o1;
#pragma unroll
        for (int u = 0; u < 8; ++u) {
            float r0 = (a[u]     + (float)sv0[u]) * dn + bsh[c16 + u];
            float r1 = (a[8 + u] + (float)sv1[u]) * dn + bsh[c16 + 8 + u];
            o0[u] = (_Float16)fmaxf(r0, 0.f);
            o1[u] = (_Float16)fmaxf(r1, 0.f);
        }
        *(half8*)(hh + (size_t)n * 128 + c16)     = o0;
        *(half8*)(hh + (size_t)n * 128 + c16 + 8) = o1;
        *(half8*)&h[nl][c16]     = o0;
        *(half8*)&h[nl][c16 + 8] = o1;
        if (cl == 0) sdv[nl] = dn;
    }
    __syncthreads();

    int quad = lane >> 4, l15 = lane & 15;
    int ko = quad * 8;
    half8 af[4];                          // A-frags of the 16 rows, shared by attn + gemm
#pragma unroll
    for (int kk = 0; kk < 4; ++kk) af[kk] = *(const half8*)&h[l15][kk * 32 + ko];

    // ---- P2: attention scores for these 16 nodes (wave w handles cols w*64..w*64+63) ----
    {
        float p[4] = {0.f, 0.f, 0.f, 0.f};
#pragma unroll
        for (int c2 = 0; c2 < 4; ++c2) {
            int ct = wave * 4 + c2;
            half8 b[4];
#pragma unroll
            for (int kk = 0; kk < 4; ++kk)
                b[kk] = *(const half8*)&WTatt[((kk * 8 + ct) * 64 + lane) * 8];
            floatx4 acc = (floatx4){0.f, 0.f, 0.f, 0.f};
#pragma unroll
            for (int kk = 0; kk < 4; ++kk)
                acc = __builtin_amdgcn_mfma_f32_16x16x32_f16(af[kk], b[kk], acc, 0, 0, 0);
            float av = a_att[ct * 16 + l15];
#pragma unroll
            for (int r = 0; r < 4; ++r) p[r] += av * fast_tanh(acc[r]);
        }
#pragma unroll
        for (int r = 0; r < 4; ++r) {
            float v = p[r];
            v += __shfl_xor(v, 1); v += __shfl_xor(v, 2);
            v += __shfl_xor(v, 4); v += __shfl_xor(v, 8);
            if (l15 == 0) pp[wave][quad * 4 + r] = v;
        }
    }
    __syncthreads();
    if (tid < 16) scores[(size_t)(n0 + tid) * 4 + layer] = pp[0][tid] + pp[1][tid];

    // ---- P3: next-layer GEMM, A from LDS ----
    if (HAS_GEMM) {
        floatx4 acc[4];
#pragma unroll
        for (int c2 = 0; c2 < 4; ++c2) acc[c2] = (floatx4){0.f, 0.f, 0.f, 0.f};
#pragma unroll
        for (int c2 = 0; c2 < 4; ++c2) {
            int ct = wave * 4 + c2;
#pragma unroll
            for (int kk = 0; kk < 4; ++kk) {
                half8 b = *(const half8*)&WTnext[((kk * 8 + ct) * 64 + lane) * 8];
                acc[c2] = __builtin_amdgcn_mfma_f32_16x16x32_f16(af[kk], b, acc[c2], 0, 0, 0);
            }
        }
        __syncthreads();   // everyone done reading h before it becomes Cs
#pragma unroll
        for (int c2 = 0; c2 < 4; ++c2) {
            int col = wave * 64 + c2 * 16 + l15;
#pragma unroll
            for (int r = 0; r < 4; ++r) {
                int row = quad * 4 + r;
                h[row][col] = (_Float16)(acc[c2][r] * sdv[row]);
            }
        }
        __syncthreads();
        int row = tid >> 3, seg = tid & 7;
        int gm = n0 + row;
        *(half8*)(hout + (size_t)gm * 128 + seg * 16)     = *(const half8*)&h[row][seg * 16];
        *(half8*)(hout + (size_t)gm * 128 + seg * 16 + 8) = *(const half8*)&h[row][seg * 16 + 8];
    }
}

// ---------------- softmax + layer-fuse (coalesced, all lanes) + MFMA out-projection ----------------
__global__ __launch_bounds__(256) void k_fuse_out(const _Float16* __restrict__ hbase, const float* __restrict__ scores,
                                                  const _Float16* __restrict__ WoutT, const float* __restrict__ bout,
                                                  float* __restrict__ out) {
    __shared__ __align__(16) _Float16 Fs[64][136];   // 17,408 B
    __shared__ float salpha[256];
    const size_t LSTR = (size_t)NNODES * 128;
    int tid = threadIdx.x;
    int n0 = blockIdx.x * 64;

    if (tid < 64) {
        int node = n0 + tid; if (node > NNODES - 1) node = NNODES - 1;
        float4 s = *(const float4*)(scores + (size_t)node * 4);
        float mx = fmaxf(fmaxf(s.x, s.y), fmaxf(s.z, s.w));
        float e0 = __expf(s.x - mx), e1 = __expf(s.y - mx), e2 = __expf(s.z - mx), e3 = __expf(s.w - mx);
        float inv = 1.0f / (e0 + e1 + e2 + e3);
        salpha[tid * 4 + 0] = e0 * inv; salpha[tid * 4 + 1] = e1 * inv;
        salpha[tid * 4 + 2] = e2 * inv; salpha[tid * 4 + 3] = e3 * inv;
    }
    __syncthreads();

    // fused = sum_l alpha_l * h_l; all 256 lanes, coalesced per (layer, j)
    {
        int no = tid >> 2, seg = tid & 3;
        int node = n0 + no; if (node > NNODES - 1) node = NNODES - 1;
        float al0 = salpha[no * 4 + 0], al1 = salpha[no * 4 + 1];
        float al2 = salpha[no * 4 + 2], al3 = salpha[no * 4 + 3];
        const _Float16* hp = hbase + (size_t)node * 128 + seg * 32;
#pragma unroll
        for (int j = 0; j < 4; ++j) {
            half8 h0 = *(const half8*)(hp + 0 * LSTR + j * 8);
            half8 h1 = *(const half8*)(hp + 1 * LSTR + j * 8);
            half8 h2 = *(const half8*)(hp + 2 * LSTR + j * 8);
            half8 h3 = *(const half8*)(hp + 3 * LSTR + j * 8);
            half8 f;
#pragma unroll
            for (int u = 0; u < 8; ++u)
                f[u] = (_Float16)(al0 * (float)h0[u] + al1 * (float)h1[u] +
                                  al2 * (float)h2[u] + al3 * (float)h3[u]);
            *(half8*)&Fs[no][seg * 32 + j * 8] = f;
        }
    }
    __syncthreads();

    // out-projection MFMA: 48 padded cols (3 frag tiles), masked fp32 write + bias
    int wave = tid >> 6, lane = tid & 63;
    int quad = lane >> 4, l15 = lane & 15;
    int ko = quad * 8;
    half8 ff[4];
    int frow = wave * 16 + l15;
#pragma unroll
    for (int kk = 0; kk < 4; ++kk) ff[kk] = *(const half8*)&Fs[frow][kk * 32 + ko];
#pragma unroll
    for (int ct = 0; ct < 3; ++ct) {
        half8 bw[4];
#pragma unroll
        for (int kk = 0; kk < 4; ++kk)
            bw[kk] = *(const half8*)(WoutT + ((kk * 3 + ct) * 64 + lane) * 8);
        floatx4 acc = (floatx4){0.f, 0.f, 0.f, 0.f};
#pragma unroll
        for (int kk = 0; kk < 4; ++kk)
            acc = __builtin_amdgcn_mfma_f32_16x16x32_f16(ff[kk], bw[kk], acc, 0, 0, 0);
        int col = ct * 16 + l15;
        if (col < NCLASS) {
            float bv = bout[col];
#pragma unroll
            for (int r = 0; r < 4; ++r) {
                int node = n0 + wave * 16 + quad * 4 + r;
                if (node < NNODES) out[(size_t)node * NCLASS + col] = acc[r] + bv;
            }
        }
    }
}

extern "C" void kernel_launch(void* const* d_in, const int* in_sizes, int n_in,
                              void* d_out, int out_size, void* d_ws, size_t ws_size,
                              hipStream_t stream) {
    const float* x     = (const float*)d_in[0];
    const int*   ei    = (const int*)d_in[1];
    const float* convW = (const float*)d_in[2];
    const float* convb = (const float*)d_in[3];
    const float* W_att = (const float*)d_in[4];
    const float* a_att = (const float*)d_in[5];
    const float* W_out = (const float*)d_in[6];
    const float* b_out = (const float*)d_in[7];
    float* out = (float*)d_out;

    char* ws = (char*)d_ws;
    size_t off = 0;
    auto take = [&](size_t nbytes) { char* p = ws + off; off += (nbytes + 255) & ~(size_t)255; return p; };
    int*       cnt     = (int*)take(NNODES * 4);
    int*       counts  = (int*)take((size_t)NCNT * 4);                   // bucket-major block counts / bases
    int*       bsum    = (int*)take(SCANB * 4);
    int2*      ebuf    = (int2*)take((size_t)NEDGES * 8);                // bucket-partitioned (src,dst)
    int*       esrc    = (int*)take((size_t)NNODES * WELL * 4 + 1024);   // ELL
    _Float16*  WoutT   = (_Float16*)take((size_t)48 * 128 * 2);
    float*     scores  = (float*)take(NNODES * 4 * 4);
    _Float16*  WT      = (_Float16*)take((size_t)5 * 128 * 128 * 2);
    _Float16*  hWsA    = (_Float16*)take((size_t)NNODES * 128 * 2);
    _Float16*  hh[4];
    for (int l = 0; l < 4; ++l) hh[l] = (_Float16*)take((size_t)NNODES * 128 * 2);
    // NOTE: hh slabs are 12,800,000 B each (multiple of 256) -> contiguous; k_fuse_out relies on it.
    _Float16*  hWsB    = (_Float16*)take((size_t)NNODES * 128 * 2);

    const int* src = ei;
    const int* dst = ei + NEDGES;

    k_hist<<<EBLK + PREPB + WOUTB, 1024, 0, stream>>>(dst, counts, convW, W_att, WT, W_out, WoutT);
    k_bsum<<<SCANB, 1024, 0, stream>>>(counts, bsum);
    k_scan<<<SCANB, 1024, 0, stream>>>(counts, bsum);
    k_part<<<EBLK, 1024, 0, stream>>>(src, dst, counts, ebuf);
    k_build<<<NB, 1024, 0, stream>>>(counts, ebuf, esrc, cnt);
    k_gemm0<<<GEMMB, 256, 0, stream>>>(x, WT, cnt, hWsA);

    // layer kernels: aggregate(l) + attention(l) + gemm(l+1); hWs ping-pongs A->B->A->B
    k_layer<true><<<XBLK, 128, 0, stream>>>(hWsA, cnt, esrc, convb + 0 * 128, hh[0],
                                            WT + 4 * 16384, a_att, scores, 0, WT + 1 * 16384, hWsB);
    k_layer<true><<<XBLK, 128, 0, stream>>>(hWsB, cnt, esrc, convb + 1 * 128, hh[1],
                                            WT + 4 * 16384, a_att, scores, 1, WT + 2 * 16384, hWsA);
    k_layer<true><<<XBLK, 128, 0, stream>>>(hWsA, cnt, esrc, convb + 2 * 128, hh[2],
                                            WT + 4 * 16384, a_att, scores, 2, WT + 3 * 16384, hWsB);
    k_layer<false><<<XBLK, 128, 0, stream>>>(hWsB, cnt, esrc, convb + 3 * 128, hh[3],
                                             WT + 4 * 16384, a_att, scores, 3, (const _Float16*)nullptr,
                                             (_Float16*)nullptr);
    k_fuse_out<<<GEMMB, 256, 0, stream>>>(hh[0], scores, WoutT, b_out, out);
}

// Round 10
// 302.961 us; speedup vs baseline: 1.0883x; 1.0014x over previous
//
#include <hip/hip_runtime.h>

#define NNODES 50000
#define NEDGES 800000
#define NCLASS 40
#define GEMMB 782      // ceil(NNODES/64)
#define XBLK  3125     // NNODES/16, 16 nodes per 128-thread layer block
#define WELL  64       // ELL width (Poisson(16) max degree ~45; 64 = huge margin)

// ---- edge-partition geometry ----
#define EBLK  782      // edge blocks of 1024 threads (800K edges)
#define PREPB 80       // 5*16384/1024 weight-prep blocks
#define WOUTB 6        // 6144/1024 WoutT-prep blocks
#define BSHIFT 10
#define NB    49       // ceil(50000/1024) coarse buckets
#define BUCKCAP 20480  // per-bucket ebuf region (mean 16384, sd~127 -> +32 sigma)

typedef _Float16 half8  __attribute__((ext_vector_type(8)));
typedef float    floatx4 __attribute__((ext_vector_type(4)));

#define CSTR 136
#define SMEM_BYTES (64 * CSTR * 2 + 256)

__device__ __forceinline__ float fast_tanh(float x) {
    return 1.0f - 2.0f / (__expf(2.0f * x) + 1.0f);
}

// ---------------- phase A: single-pass bucket partition | weight prep (frag order) ----------------
// Per block: LDS histogram of 49 coarse buckets -> ONE global atomicAdd per (block,bucket) claims a
// disjoint range in the bucket's fixed ebuf region -> write (src,dst) in ~21-edge contiguous runs.
// Replaces R8's hist+bsum+scan+part (4 kernels, one extra 3.2MB edge read, 20-barrier ladder scan).
// Defensive clamps on statistically-impossible overflows (cheap, off hot path).
// Fragment layout (per 128x128 mat): element (n = ct*16 + l15, k = kk*32 + quad*8 + j)
// stored at ((kk*8 + ct)*64 + quad*16 + l15)*8 + j.
__global__ __launch_bounds__(1024) void k_part(const int* __restrict__ src, const int* __restrict__ dst,
                                               int* __restrict__ gbase, int2* __restrict__ ebuf,
                                               const float* __restrict__ convW, const float* __restrict__ W_att,
                                               _Float16* __restrict__ WT,
                                               const float* __restrict__ Wout, _Float16* __restrict__ WoutT) {
    int bid = blockIdx.x, tid = threadIdx.x;
    if (bid < EBLK) {
        __shared__ int hist[NB];
        __shared__ int base[NB];
        if (tid < NB) hist[tid] = 0;
        __syncthreads();
        int e = bid * 1024 + tid;
        bool ok = e < NEDGES;
        int s = 0, d = 0, b = 0, slot = 0;
        if (ok) {
            d = dst[e];
            s = src[e];
            b = d >> BSHIFT;
            slot = atomicAdd(&hist[b], 1);
        }
        __syncthreads();
        if (tid < NB) base[tid] = atomicAdd(&gbase[tid * 32], hist[tid]);   // padded counters: 1/line
        __syncthreads();
        if (ok) {
            int pos = base[b] + slot;
            if (pos < BUCKCAP) ebuf[(size_t)b * BUCKCAP + pos] = make_int2(s, d);   // clamp: ~32-sigma guard
        }
    } else if (bid < EBLK + PREPB) {
        int idx = (bid - EBLK) * 1024 + tid;   // < 5*16384
        int mat = idx >> 14, rem = idx & 16383;
        int j = rem & 7, lane = (rem >> 3) & 63, tile = rem >> 9;
        int l15 = lane & 15, quad = lane >> 4;
        int ct = tile & 7, kk = tile >> 3;
        int n = ct * 16 + l15, k = kk * 32 + quad * 8 + j;
        const float* s = (mat < 4) ? (convW + mat * 16384) : W_att;
        WT[idx] = (_Float16)s[k * 128 + n];
    } else {
        int idx = (bid - EBLK - PREPB) * 1024 + tid;   // < 6144
        int j = idx & 7, lane = (idx >> 3) & 63, tile = idx >> 9;
        int l15 = lane & 15, quad = lane >> 4;
        int ct = tile % 3, kk = tile / 3;
        int n = ct * 16 + l15, k = kk * 32 + quad * 8 + j;
        WoutT[idx] = (n < NCLASS) ? (_Float16)Wout[k * NCLASS + n] : (_Float16)0.f;
    }
}

// ---------------- phase B: per-bucket ELL build; esrc writes land in a 256KB L2-resident window ----
__global__ __launch_bounds__(1024) void k_build(const int* __restrict__ gbase, const int2* __restrict__ ebuf,
                                                int* __restrict__ esrc, int* __restrict__ cnt) {
    __shared__ int lcnt[1024];
    int b = blockIdx.x, t = threadIdx.x;
    lcnt[t] = 0;
    __syncthreads();
    int n0 = b << BSHIFT;
    int total = gbase[b * 32];
    if (total > BUCKCAP) total = BUCKCAP;          // clamp (mirror of k_part guard)
    const int2* ep = ebuf + (size_t)b * BUCKCAP;
    for (int i = t; i < total; i += 1024) {
        int2 p = ep[i];
        int slot = atomicAdd(&lcnt[p.y - n0], 1);
        if (slot < WELL) esrc[p.y * WELL + slot] = p.x;   // clamp: degree > 64 is ~1e-17
    }
    __syncthreads();
    int n = n0 + t;
    if (n < NNODES) cnt[n] = (lcnt[t] < WELL) ? lcnt[t] : WELL;
}

// ---------------- 64-row GEMM (layer-0 only, fp32 A): C = (A @ W) * dinv; dinv from cnt ------------
__global__ __launch_bounds__(256) void k_gemm0(const float* __restrict__ Av, const _Float16* __restrict__ WTf,
                                               const int* __restrict__ cnt, _Float16* __restrict__ C) {
    __shared__ __align__(16) char smem[SMEM_BYTES];
    _Float16 (*Csh)[CSTR] = (_Float16 (*)[CSTR])smem;
    float* sdinv = (float*)(smem + 64 * CSTR * 2);
    int m0 = blockIdx.x * 64;
    int tid = threadIdx.x;
    int wave = tid >> 6, lane = tid & 63;
    int quad = lane >> 4, l15 = lane & 15;
    int ko = quad * 8;

    if (tid < 64) {
        int r = m0 + tid; if (r > NNODES - 1) r = NNODES - 1;
        sdinv[tid] = rsqrtf((float)cnt[r] + 1.0f);
    }

    floatx4 acc[4][2];
#pragma unroll
    for (int rt = 0; rt < 4; ++rt)
#pragma unroll
        for (int ct = 0; ct < 2; ++ct) acc[rt][ct] = (floatx4){0.f, 0.f, 0.f, 0.f};

#pragma unroll
    for (int kk = 0; kk < 4; ++kk) {
        half8 a[4], b[2];
#pragma unroll
        for (int rt = 0; rt < 4; ++rt) {
            int row = m0 + rt * 16 + l15;
            if (row > NNODES - 1) row = NNODES - 1;
            const float* Ap = Av + (size_t)row * 128 + kk * 32 + ko;
            float4 f0 = *(const float4*)Ap;
            float4 f1 = *(const float4*)(Ap + 4);
            a[rt] = (half8){(_Float16)f0.x, (_Float16)f0.y, (_Float16)f0.z, (_Float16)f0.w,
                            (_Float16)f1.x, (_Float16)f1.y, (_Float16)f1.z, (_Float16)f1.w};
        }
#pragma unroll
        for (int ct = 0; ct < 2; ++ct)
            b[ct] = *(const half8*)&WTf[((kk * 8 + (wave * 2 + ct)) * 64 + lane) * 8];
#pragma unroll
        for (int rt = 0; rt < 4; ++rt)
#pragma unroll
            for (int ct = 0; ct < 2; ++ct)
                acc[rt][ct] = __builtin_amdgcn_mfma_f32_16x16x32_f16(a[rt], b[ct], acc[rt][ct], 0, 0, 0);
    }
    __syncthreads();   // sdinv visible

#pragma unroll
    for (int rt = 0; rt < 4; ++rt)
#pragma unroll
        for (int r = 0; r < 4; ++r) {
            float d = sdinv[rt * 16 + quad * 4 + r];
#pragma unroll
            for (int ct = 0; ct < 2; ++ct)
                Csh[rt * 16 + quad * 4 + r][wave * 32 + ct * 16 + l15] = (_Float16)(acc[rt][ct][r] * d);
        }
    __syncthreads();

    int row = tid >> 2, seg = tid & 3;
    int gm = m0 + row;
    if (gm < NNODES) {
#pragma unroll
        for (int j = 0; j < 4; ++j)
            *(half8*)(C + (size_t)gm * 128 + seg * 32 + j * 8) = *(const half8*)&Csh[row][seg * 32 + j * 8];
    }
}

// ---------------- fused layer kernel: aggregate(l) | attention(l) | gemm(l+1) ----------------
// Block = 128 threads (2 waves), 16 nodes. Aggregation: 8 lanes/node, 4-deep pipelined gathers.
// ELL edge list: beg = n*WELL, end = beg + cnt[n]. Post-relu h kept in LDS -> attention and
// next-layer GEMM read it from LDS. Gathers read hin; gemm writes hout (ping-pong, no race).
template <bool HAS_GEMM>
__global__ __launch_bounds__(128) void k_layer(const _Float16* __restrict__ hin,
                                               const int* __restrict__ cnt, const int* __restrict__ esrc,
                                               const float* __restrict__ bias,
                                               _Float16* __restrict__ hh,
                                               const _Float16* __restrict__ WTatt, const float* __restrict__ a_att,
                                               float* __restrict__ scores, int layer,
                                               const _Float16* __restrict__ WTnext, _Float16* __restrict__ hout) {
    __shared__ __align__(16) _Float16 h[16][CSTR];   // 4,352 B; reused as Cs in the gemm epilogue
    __shared__ float bsh[128];
    __shared__ float sdv[16];
    __shared__ float pp[2][16];
    int tid = threadIdx.x;
    bsh[tid] = bias[tid];
    int wave = tid >> 6, lane = tid & 63;
    int n0 = blockIdx.x * 16;

    // ---- P1: aggregate 16 nodes (8 lanes per node, 16 channels per lane) ----
    {
        int nl = tid >> 3;               // 0..15
        int cl = tid & 7;
        int c16 = cl * 16;
        int n = n0 + nl;                 // XBLK*16 == NNODES: always valid
        int cv = cnt[n];
        int beg = n * WELL, end = beg + cv;
        float dn = rsqrtf((float)cv + 1.0f);
        const _Float16* sp = hin + (size_t)n * 128 + c16;
        half8 sv0 = *(const half8*)sp;
        half8 sv1 = *(const half8*)(sp + 8);

        float a[16];
#pragma unroll
        for (int u = 0; u < 16; ++u) a[u] = 0.f;

        int idxA[4]; float mskA[4];
#pragma unroll
        for (int i = 0; i < 4; ++i) {
            int ei = beg + i;
            int t = esrc[ei];            // within the 64-slot row: always in-bounds
            bool ok = ei < end;
            idxA[i] = ok ? t : n;
            mskA[i] = ok ? 1.f : 0.f;
        }
        for (int e = beg; e < end; e += 4) {
            half8 v0[4], v1[4];
#pragma unroll
            for (int i = 0; i < 4; ++i) {
                const _Float16* p = hin + (size_t)idxA[i] * 128 + c16;
                v0[i] = *(const half8*)p;
                v1[i] = *(const half8*)(p + 8);
            }
            int idxB[4]; float mskB[4];
#pragma unroll
            for (int i = 0; i < 4; ++i) {
                int ei = e + 4 + i;
                int t = esrc[ei];        // within row (cv+8 <= 53 < 64)
                bool ok = ei < end;
                idxB[i] = ok ? t : n;
                mskB[i] = ok ? 1.f : 0.f;
            }
#pragma unroll
            for (int i = 0; i < 4; ++i) {
                float m = mskA[i];
#pragma unroll
                for (int u = 0; u < 8; ++u) {
                    a[u]     += m * (float)v0[i][u];
                    a[8 + u] += m * (float)v1[i][u];
                }
            }
#pragma unroll
            for (int i = 0; i < 4; ++i) { idxA[i] = idxB[i]; mskA[i] = mskB[i]; }
        }
        __syncthreads();   // bsh ready
        half8 o0, o1;
#pragma unroll
        for (int u = 0; u < 8; ++u) {
            float r0 = (a[u]     + (float)sv0[u]) * dn + bsh[c16 + u];
            float r1 = (a[8 + u] + (float)sv1[u]) * dn + bsh[c16 + 8 + u];
            o0[u] = (_Float16)fmaxf(r0, 0.f);
            o1[u] = (_Float16)fmaxf(r1, 0.f);
        }
        *(half8*)(hh + (size_t)n * 128 + c16)     = o0;
        *(half8*)(hh + (size_t)n * 128 + c16 + 8) = o1;
        *(half8*)&h[nl][c16]     = o0;
        *(half8*)&h[nl][c16 + 8] = o1;
        if (cl == 0) sdv[nl] = dn;
    }
    __syncthreads();

    int quad = lane >> 4, l15 = lane & 15;
    int ko = quad * 8;
    half8 af[4];                          // A-frags of the 16 rows, shared by attn + gemm
#pragma unroll
    for (int kk = 0; kk < 4; ++kk) af[kk] = *(const half8*)&h[l15][kk * 32 + ko];

    // ---- P2: attention scores for these 16 nodes (wave w handles cols w*64..w*64+63) ----
    {
        float p[4] = {0.f, 0.f, 0.f, 0.f};
#pragma unroll
        for (int c2 = 0; c2 < 4; ++c2) {
            int ct = wave * 4 + c2;
            half8 b[4];
#pragma unroll
            for (int kk = 0; kk < 4; ++kk)
                b[kk] = *(const half8*)&WTatt[((kk * 8 + ct) * 64 + lane) * 8];
            floatx4 acc = (floatx4){0.f, 0.f, 0.f, 0.f};
#pragma unroll
            for (int kk = 0; kk < 4; ++kk)
                acc = __builtin_amdgcn_mfma_f32_16x16x32_f16(af[kk], b[kk], acc, 0, 0, 0);
            float av = a_att[ct * 16 + l15];
#pragma unroll
            for (int r = 0; r < 4; ++r) p[r] += av * fast_tanh(acc[r]);
        }
#pragma unroll
        for (int r = 0; r < 4; ++r) {
            float v = p[r];
            v += __shfl_xor(v, 1); v += __shfl_xor(v, 2);
            v += __shfl_xor(v, 4); v += __shfl_xor(v, 8);
            if (l15 == 0) pp[wave][quad * 4 + r] = v;
        }
    }
    __syncthreads();
    if (tid < 16) scores[(size_t)(n0 + tid) * 4 + layer] = pp[0][tid] + pp[1][tid];

    // ---- P3: next-layer GEMM, A from LDS ----
    if (HAS_GEMM) {
        floatx4 acc[4];
#pragma unroll
        for (int c2 = 0; c2 < 4; ++c2) acc[c2] = (floatx4){0.f, 0.f, 0.f, 0.f};
#pragma unroll
        for (int c2 = 0; c2 < 4; ++c2) {
            int ct = wave * 4 + c2;
#pragma unroll
            for (int kk = 0; kk < 4; ++kk) {
                half8 b = *(const half8*)&WTnext[((kk * 8 + ct) * 64 + lane) * 8];
                acc[c2] = __builtin_amdgcn_mfma_f32_16x16x32_f16(af[kk], b, acc[c2], 0, 0, 0);
            }
        }
        __syncthreads();   // everyone done reading h before it becomes Cs
#pragma unroll
        for (int c2 = 0; c2 < 4; ++c2) {
            int col = wave * 64 + c2 * 16 + l15;
#pragma unroll
            for (int r = 0; r < 4; ++r) {
                int row = quad * 4 + r;
                h[row][col] = (_Float16)(acc[c2][r] * sdv[row]);
            }
        }
        __syncthreads();
        int row = tid >> 3, seg = tid & 7;
        int gm = n0 + row;
        *(half8*)(hout + (size_t)gm * 128 + seg * 16)     = *(const half8*)&h[row][seg * 16];
        *(half8*)(hout + (size_t)gm * 128 + seg * 16 + 8) = *(const half8*)&h[row][seg * 16 + 8];
    }
}

// ---------------- softmax + layer-fuse (coalesced, all lanes) + MFMA out-projection ----------------
__global__ __launch_bounds__(256) void k_fuse_out(const _Float16* __restrict__ hbase, const float* __restrict__ scores,
                                                  const _Float16* __restrict__ WoutT, const float* __restrict__ bout,
                                                  float* __restrict__ out) {
    __shared__ __align__(16) _Float16 Fs[64][136];   // 17,408 B
    __shared__ float salpha[256];
    const size_t LSTR = (size_t)NNODES * 128;
    int tid = threadIdx.x;
    int n0 = blockIdx.x * 64;

    if (tid < 64) {
        int node = n0 + tid; if (node > NNODES - 1) node = NNODES - 1;
        float4 s = *(const float4*)(scores + (size_t)node * 4);
        float mx = fmaxf(fmaxf(s.x, s.y), fmaxf(s.z, s.w));
        float e0 = __expf(s.x - mx), e1 = __expf(s.y - mx), e2 = __expf(s.z - mx), e3 = __expf(s.w - mx);
        float inv = 1.0f / (e0 + e1 + e2 + e3);
        salpha[tid * 4 + 0] = e0 * inv; salpha[tid * 4 + 1] = e1 * inv;
        salpha[tid * 4 + 2] = e2 * inv; salpha[tid * 4 + 3] = e3 * inv;
    }
    __syncthreads();

    // fused = sum_l alpha_l * h_l; all 256 lanes, coalesced per (layer, j)
    {
        int no = tid >> 2, seg = tid & 3;
        int node = n0 + no; if (node > NNODES - 1) node = NNODES - 1;
        float al0 = salpha[no * 4 + 0], al1 = salpha[no * 4 + 1];
        float al2 = salpha[no * 4 + 2], al3 = salpha[no * 4 + 3];
        const _Float16* hp = hbase + (size_t)node * 128 + seg * 32;
#pragma unroll
        for (int j = 0; j < 4; ++j) {
            half8 h0 = *(const half8*)(hp + 0 * LSTR + j * 8);
            half8 h1 = *(const half8*)(hp + 1 * LSTR + j * 8);
            half8 h2 = *(const half8*)(hp + 2 * LSTR + j * 8);
            half8 h3 = *(const half8*)(hp + 3 * LSTR + j * 8);
            half8 f;
#pragma unroll
            for (int u = 0; u < 8; ++u)
                f[u] = (_Float16)(al0 * (float)h0[u] + al1 * (float)h1[u] +
                                  al2 * (float)h2[u] + al3 * (float)h3[u]);
            *(half8*)&Fs[no][seg * 32 + j * 8] = f;
        }
    }
    __syncthreads();

    // out-projection MFMA: 48 padded cols (3 frag tiles), masked fp32 write + bias
    int wave = tid >> 6, lane = tid & 63;
    int quad = lane >> 4, l15 = lane & 15;
    int ko = quad * 8;
    half8 ff[4];
    int frow = wave * 16 + l15;
#pragma unroll
    for (int kk = 0; kk < 4; ++kk) ff[kk] = *(const half8*)&Fs[frow][kk * 32 + ko];
#pragma unroll
    for (int ct = 0; ct < 3; ++ct) {
        half8 bw[4];
#pragma unroll
        for (int kk = 0; kk < 4; ++kk)
            bw[kk] = *(const half8*)(WoutT + ((kk * 3 + ct) * 64 + lane) * 8);
        floatx4 acc = (floatx4){0.f, 0.f, 0.f, 0.f};
#pragma unroll
        for (int kk = 0; kk < 4; ++kk)
            acc = __builtin_amdgcn_mfma_f32_16x16x32_f16(ff[kk], bw[kk], acc, 0, 0, 0);
        int col = ct * 16 + l15;
        if (col < NCLASS) {
            float bv = bout[col];
#pragma unroll
            for (int r = 0; r < 4; ++r) {
                int node = n0 + wave * 16 + quad * 4 + r;
                if (node < NNODES) out[(size_t)node * NCLASS + col] = acc[r] + bv;
            }
        }
    }
}

extern "C" void kernel_launch(void* const* d_in, const int* in_sizes, int n_in,
                              void* d_out, int out_size, void* d_ws, size_t ws_size,
                              hipStream_t stream) {
    const float* x     = (const float*)d_in[0];
    const int*   ei    = (const int*)d_in[1];
    const float* convW = (const float*)d_in[2];
    const float* convb = (const float*)d_in[3];
    const float* W_att = (const float*)d_in[4];
    const float* a_att = (const float*)d_in[5];
    const float* W_out = (const float*)d_in[6];
    const float* b_out = (const float*)d_in[7];
    float* out = (float*)d_out;

    char* ws = (char*)d_ws;
    size_t off = 0;
    auto take = [&](size_t nbytes) { char* p = ws + off; off += (nbytes + 255) & ~(size_t)255; return p; };
    int*       cnt     = (int*)take(NNODES * 4);
    int*       gbase   = (int*)take((size_t)NB * 32 * 4);                // padded bucket counters
    int2*      ebuf    = (int2*)take((size_t)NB * BUCKCAP * 8);          // fixed per-bucket regions
    int*       esrc    = (int*)take((size_t)NNODES * WELL * 4 + 1024);   // ELL
    _Float16*  WoutT   = (_Float16*)take((size_t)48 * 128 * 2);
    float*     scores  = (float*)take(NNODES * 4 * 4);
    _Float16*  WT      = (_Float16*)take((size_t)5 * 128 * 128 * 2);
    _Float16*  hWsA    = (_Float16*)take((size_t)NNODES * 128 * 2);
    _Float16*  hh[4];
    for (int l = 0; l < 4; ++l) hh[l] = (_Float16*)take((size_t)NNODES * 128 * 2);
    // NOTE: hh slabs are 12,800,000 B each (multiple of 256) -> contiguous; k_fuse_out relies on it.
    _Float16*  hWsB    = (_Float16*)take((size_t)NNODES * 128 * 2);

    const int* src = ei;
    const int* dst = ei + NEDGES;

    hipMemsetAsync(gbase, 0, (size_t)NB * 32 * 4, stream);
    k_part<<<EBLK + PREPB + WOUTB, 1024, 0, stream>>>(src, dst, gbase, ebuf, convW, W_att, WT, W_out, WoutT);
    k_build<<<NB, 1024, 0, stream>>>(gbase, ebuf, esrc, cnt);
    k_gemm0<<<GEMMB, 256, 0, stream>>>(x, WT, cnt, hWsA);

    // layer kernels: aggregate(l) + attention(l) + gemm(l+1); hWs ping-pongs A->B->A->B
    k_layer<true><<<XBLK, 128, 0, stream>>>(hWsA, cnt, esrc, convb + 0 * 128, hh[0],
                                            WT + 4 * 16384, a_att, scores, 0, WT + 1 * 16384, hWsB);
    k_layer<true><<<XBLK, 128, 0, stream>>>(hWsB, cnt, esrc, convb + 1 * 128, hh[1],
                                            WT + 4 * 16384, a_att, scores, 1, WT + 2 * 16384, hWsA);
    k_layer<true><<<XBLK, 128, 0, stream>>>(hWsA, cnt, esrc, convb + 2 * 128, hh[2],
                                            WT + 4 * 16384, a_att, scores, 2, WT + 3 * 16384, hWsB);
    k_layer<false><<<XBLK, 128, 0, stream>>>(hWsB, cnt, esrc, convb + 3 * 128, hh[3],
                                             WT + 4 * 16384, a_att, scores, 3, (const _Float16*)nullptr,
                                             (_Float16*)nullptr);
    k_fuse_out<<<GEMMB, 256, 0, stream>>>(hh[0], scores, WoutT, b_out, out);
}

// Round 11
// 286.424 us; speedup vs baseline: 1.1512x; 1.0577x over previous
//
#include <hip/hip_runtime.h>

#define NNODES 50000
#define NEDGES 800000
#define NCLASS 40
#define GEMMB 782      // ceil(NNODES/64)
#define XBLK  3125     // NNODES/16, 16 nodes per 128-thread layer block
#define WELL  64       // ELL width (Poisson(16) max degree ~45; 64 = huge margin)

// ---- edge-partition geometry ----
#define EBLK  782      // edge blocks of 1024 threads (800K edges)
#define PREPB 80       // 5*16384/1024 weight-prep blocks
#define WOUTB 6        // 6144/1024 WoutT-prep blocks
#define BSHIFT 10
#define NB    49       // ceil(50000/1024) coarse buckets
#define BUCKCAP 20480  // per-bucket ebuf region (mean 16384, sd~127 -> +32 sigma)

typedef _Float16 half8  __attribute__((ext_vector_type(8)));
typedef float    floatx4 __attribute__((ext_vector_type(4)));

#define CSTR 136
#define SMEM_BYTES (64 * CSTR * 2 + 256)

__device__ __forceinline__ float fast_tanh(float x) {
    return 1.0f - 2.0f / (__expf(2.0f * x) + 1.0f);
}

// ---------------- phase A: single-pass bucket partition | weight prep (frag order) ----------------
// Per block: LDS histogram of 49 coarse buckets -> ONE global atomicAdd per (block,bucket) claims a
// disjoint range in the bucket's fixed ebuf region -> write PACKED (doff<<16|src) in ~21-edge runs
// (src < 65536, doff < 1024: fits 32b; halves scatter bytes vs int2).
// Fragment layout (per 128x128 mat): element (n = ct*16 + l15, k = kk*32 + quad*8 + j)
// stored at ((kk*8 + ct)*64 + quad*16 + l15)*8 + j.
__global__ __launch_bounds__(1024) void k_part(const int* __restrict__ src, const int* __restrict__ dst,
                                               int* __restrict__ gbase, unsigned int* __restrict__ ebuf,
                                               const float* __restrict__ convW, const float* __restrict__ W_att,
                                               _Float16* __restrict__ WT,
                                               const float* __restrict__ Wout, _Float16* __restrict__ WoutT) {
    int bid = blockIdx.x, tid = threadIdx.x;
    if (bid < EBLK) {
        __shared__ int hist[NB];
        __shared__ int base[NB];
        if (tid < NB) hist[tid] = 0;
        __syncthreads();
        int e = bid * 1024 + tid;
        bool ok = e < NEDGES;
        int s = 0, d = 0, b = 0, slot = 0;
        if (ok) {
            d = dst[e];
            s = src[e];
            b = d >> BSHIFT;
            slot = atomicAdd(&hist[b], 1);
        }
        __syncthreads();
        if (tid < NB) base[tid] = atomicAdd(&gbase[tid * 32], hist[tid]);   // padded counters: 1/line
        __syncthreads();
        if (ok) {
            int pos = base[b] + slot;
            unsigned int packed = ((unsigned int)(d & ((1 << BSHIFT) - 1)) << 16) | (unsigned int)s;
            if (pos < BUCKCAP) ebuf[(size_t)b * BUCKCAP + pos] = packed;    // clamp: ~32-sigma guard
        }
    } else if (bid < EBLK + PREPB) {
        int idx = (bid - EBLK) * 1024 + tid;   // < 5*16384
        int mat = idx >> 14, rem = idx & 16383;
        int j = rem & 7, lane = (rem >> 3) & 63, tile = rem >> 9;
        int l15 = lane & 15, quad = lane >> 4;
        int ct = tile & 7, kk = tile >> 3;
        int n = ct * 16 + l15, k = kk * 32 + quad * 8 + j;
        const float* s = (mat < 4) ? (convW + mat * 16384) : W_att;
        WT[idx] = (_Float16)s[k * 128 + n];
    } else {
        int idx = (bid - EBLK - PREPB) * 1024 + tid;   // < 6144
        int j = idx & 7, lane = (idx >> 3) & 63, tile = idx >> 9;
        int l15 = lane & 15, quad = lane >> 4;
        int ct = tile % 3, kk = tile / 3;
        int n = ct * 16 + l15, k = kk * 32 + quad * 8 + j;
        WoutT[idx] = (n < NCLASS) ? (_Float16)Wout[k * NCLASS + n] : (_Float16)0.f;
    }
}

// ---------------- phase B: per-bucket ELL build; esrc writes land in a 256KB L2-resident window ----
__global__ __launch_bounds__(1024) void k_build(const int* __restrict__ gbase,
                                                const unsigned int* __restrict__ ebuf,
                                                int* __restrict__ esrc, int* __restrict__ cnt) {
    __shared__ int lcnt[1024];
    int b = blockIdx.x, t = threadIdx.x;
    lcnt[t] = 0;
    __syncthreads();
    int n0 = b << BSHIFT;
    int total = gbase[b * 32];
    if (total > BUCKCAP) total = BUCKCAP;          // clamp (mirror of k_part guard)
    const unsigned int* ep = ebuf + (size_t)b * BUCKCAP;
    for (int i = t; i < total; i += 1024) {
        unsigned int p = ep[i];
        int doff = (int)(p >> 16);
        int s = (int)(p & 0xFFFFu);
        int slot = atomicAdd(&lcnt[doff], 1);
        if (slot < WELL) esrc[(n0 + doff) * WELL + slot] = s;   // clamp: degree > 64 is ~1e-17
    }
    __syncthreads();
    int n = n0 + t;
    if (n < NNODES) cnt[n] = (lcnt[t] < WELL) ? lcnt[t] : WELL;
}

// ---------------- 64-row GEMM (layer-0 only, fp32 A): C = (A @ W) * dinv; dinv from cnt ------------
__global__ __launch_bounds__(256) void k_gemm0(const float* __restrict__ Av, const _Float16* __restrict__ WTf,
                                               const int* __restrict__ cnt, _Float16* __restrict__ C) {
    __shared__ __align__(16) char smem[SMEM_BYTES];
    _Float16 (*Csh)[CSTR] = (_Float16 (*)[CSTR])smem;
    float* sdinv = (float*)(smem + 64 * CSTR * 2);
    int m0 = blockIdx.x * 64;
    int tid = threadIdx.x;
    int wave = tid >> 6, lane = tid & 63;
    int quad = lane >> 4, l15 = lane & 15;
    int ko = quad * 8;

    if (tid < 64) {
        int r = m0 + tid; if (r > NNODES - 1) r = NNODES - 1;
        sdinv[tid] = rsqrtf((float)cnt[r] + 1.0f);
    }

    floatx4 acc[4][2];
#pragma unroll
    for (int rt = 0; rt < 4; ++rt)
#pragma unroll
        for (int ct = 0; ct < 2; ++ct) acc[rt][ct] = (floatx4){0.f, 0.f, 0.f, 0.f};

#pragma unroll
    for (int kk = 0; kk < 4; ++kk) {
        half8 a[4], b[2];
#pragma unroll
        for (int rt = 0; rt < 4; ++rt) {
            int row = m0 + rt * 16 + l15;
            if (row > NNODES - 1) row = NNODES - 1;
            const float* Ap = Av + (size_t)row * 128 + kk * 32 + ko;
            float4 f0 = *(const float4*)Ap;
            float4 f1 = *(const float4*)(Ap + 4);
            a[rt] = (half8){(_Float16)f0.x, (_Float16)f0.y, (_Float16)f0.z, (_Float16)f0.w,
                            (_Float16)f1.x, (_Float16)f1.y, (_Float16)f1.z, (_Float16)f1.w};
        }
#pragma unroll
        for (int ct = 0; ct < 2; ++ct)
            b[ct] = *(const half8*)&WTf[((kk * 8 + (wave * 2 + ct)) * 64 + lane) * 8];
#pragma unroll
        for (int rt = 0; rt < 4; ++rt)
#pragma unroll
            for (int ct = 0; ct < 2; ++ct)
                acc[rt][ct] = __builtin_amdgcn_mfma_f32_16x16x32_f16(a[rt], b[ct], acc[rt][ct], 0, 0, 0);
    }
    __syncthreads();   // sdinv visible

#pragma unroll
    for (int rt = 0; rt < 4; ++rt)
#pragma unroll
        for (int r = 0; r < 4; ++r) {
            float d = sdinv[rt * 16 + quad * 4 + r];
#pragma unroll
            for (int ct = 0; ct < 2; ++ct)
                Csh[rt * 16 + quad * 4 + r][wave * 32 + ct * 16 + l15] = (_Float16)(acc[rt][ct][r] * d);
        }
    __syncthreads();

    int row = tid >> 2, seg = tid & 3;
    int gm = m0 + row;
    if (gm < NNODES) {
#pragma unroll
        for (int j = 0; j < 4; ++j)
            *(half8*)(C + (size_t)gm * 128 + seg * 32 + j * 8) = *(const half8*)&Csh[row][seg * 32 + j * 8];
    }
}

// ---------------- fused layer kernel (layers 0-2): aggregate(l) | attention(l) | gemm(l+1) --------
// Block = 128 threads (2 waves), 16 nodes. Aggregation: 8 lanes/node, 4-deep pipelined gathers.
// ELL edge list: beg = n*WELL, end = beg + cnt[n]. Post-relu h kept in LDS -> attention and
// next-layer GEMM read it from LDS. Gathers read hin; gemm writes hout (ping-pong, no race).
__global__ __launch_bounds__(128) void k_layer(const _Float16* __restrict__ hin,
                                               const int* __restrict__ cnt, const int* __restrict__ esrc,
                                               const float* __restrict__ bias,
                                               _Float16* __restrict__ hh,
                                               const _Float16* __restrict__ WTatt, const float* __restrict__ a_att,
                                               float* __restrict__ scores, int layer,
                                               const _Float16* __restrict__ WTnext, _Float16* __restrict__ hout) {
    __shared__ __align__(16) _Float16 h[16][CSTR];   // 4,352 B; reused as Cs in the gemm epilogue
    __shared__ float bsh[128];
    __shared__ float sdv[16];
    __shared__ float pp[2][16];
    int tid = threadIdx.x;
    bsh[tid] = bias[tid];
    int wave = tid >> 6, lane = tid & 63;
    int n0 = blockIdx.x * 16;

    // ---- P1: aggregate 16 nodes (8 lanes per node, 16 channels per lane) ----
    {
        int nl = tid >> 3;               // 0..15
        int cl = tid & 7;
        int c16 = cl * 16;
        int n = n0 + nl;                 // XBLK*16 == NNODES: always valid
        int cv = cnt[n];
        int beg = n * WELL, end = beg + cv;
        float dn = rsqrtf((float)cv + 1.0f);
        const _Float16* sp = hin + (size_t)n * 128 + c16;
        half8 sv0 = *(const half8*)sp;
        half8 sv1 = *(const half8*)(sp + 8);

        float a[16];
#pragma unroll
        for (int u = 0; u < 16; ++u) a[u] = 0.f;

        int idxA[4]; float mskA[4];
#pragma unroll
        for (int i = 0; i < 4; ++i) {
            int ei = beg + i;
            int t = esrc[ei];            // within the 64-slot row: always in-bounds
            bool ok = ei < end;
            idxA[i] = ok ? t : n;
            mskA[i] = ok ? 1.f : 0.f;
        }
        for (int e = beg; e < end; e += 4) {
            half8 v0[4], v1[4];
#pragma unroll
            for (int i = 0; i < 4; ++i) {
                const _Float16* p = hin + (size_t)idxA[i] * 128 + c16;
                v0[i] = *(const half8*)p;
                v1[i] = *(const half8*)(p + 8);
            }
            int idxB[4]; float mskB[4];
#pragma unroll
            for (int i = 0; i < 4; ++i) {
                int ei = e + 4 + i;
                int t = esrc[ei];        // within row (cv+8 <= 53 < 64)
                bool ok = ei < end;
                idxB[i] = ok ? t : n;
                mskB[i] = ok ? 1.f : 0.f;
            }
#pragma unroll
            for (int i = 0; i < 4; ++i) {
                float m = mskA[i];
#pragma unroll
                for (int u = 0; u < 8; ++u) {
                    a[u]     += m * (float)v0[i][u];
                    a[8 + u] += m * (float)v1[i][u];
                }
            }
#pragma unroll
            for (int i = 0; i < 4; ++i) { idxA[i] = idxB[i]; mskA[i] = mskB[i]; }
        }
        __syncthreads();   // bsh ready
        half8 o0, o1;
#pragma unroll
        for (int u = 0; u < 8; ++u) {
            float r0 = (a[u]     + (float)sv0[u]) * dn + bsh[c16 + u];
            float r1 = (a[8 + u] + (float)sv1[u]) * dn + bsh[c16 + 8 + u];
            o0[u] = (_Float16)fmaxf(r0, 0.f);
            o1[u] = (_Float16)fmaxf(r1, 0.f);
        }
        *(half8*)(hh + (size_t)n * 128 + c16)     = o0;
        *(half8*)(hh + (size_t)n * 128 + c16 + 8) = o1;
        *(half8*)&h[nl][c16]     = o0;
        *(half8*)&h[nl][c16 + 8] = o1;
        if (cl == 0) sdv[nl] = dn;
    }
    __syncthreads();

    int quad = lane >> 4, l15 = lane & 15;
    int ko = quad * 8;
    half8 af[4];                          // A-frags of the 16 rows, shared by attn + gemm
#pragma unroll
    for (int kk = 0; kk < 4; ++kk) af[kk] = *(const half8*)&h[l15][kk * 32 + ko];

    // ---- P2: attention scores for these 16 nodes (wave w handles cols w*64..w*64+63) ----
    {
        float p[4] = {0.f, 0.f, 0.f, 0.f};
#pragma unroll
        for (int c2 = 0; c2 < 4; ++c2) {
            int ct = wave * 4 + c2;
            half8 b[4];
#pragma unroll
            for (int kk = 0; kk < 4; ++kk)
                b[kk] = *(const half8*)&WTatt[((kk * 8 + ct) * 64 + lane) * 8];
            floatx4 acc = (floatx4){0.f, 0.f, 0.f, 0.f};
#pragma unroll
            for (int kk = 0; kk < 4; ++kk)
                acc = __builtin_amdgcn_mfma_f32_16x16x32_f16(af[kk], b[kk], acc, 0, 0, 0);
            float av = a_att[ct * 16 + l15];
#pragma unroll
            for (int r = 0; r < 4; ++r) p[r] += av * fast_tanh(acc[r]);
        }
#pragma unroll
        for (int r = 0; r < 4; ++r) {
            float v = p[r];
            v += __shfl_xor(v, 1); v += __shfl_xor(v, 2);
            v += __shfl_xor(v, 4); v += __shfl_xor(v, 8);
            if (l15 == 0) pp[wave][quad * 4 + r] = v;
        }
    }
    __syncthreads();
    if (tid < 16) scores[(size_t)(n0 + tid) * 4 + layer] = pp[0][tid] + pp[1][tid];

    // ---- P3: next-layer GEMM, A from LDS ----
    {
        floatx4 acc[4];
#pragma unroll
        for (int c2 = 0; c2 < 4; ++c2) acc[c2] = (floatx4){0.f, 0.f, 0.f, 0.f};
#pragma unroll
        for (int c2 = 0; c2 < 4; ++c2) {
            int ct = wave * 4 + c2;
#pragma unroll
            for (int kk = 0; kk < 4; ++kk) {
                half8 b = *(const half8*)&WTnext[((kk * 8 + ct) * 64 + lane) * 8];
                acc[c2] = __builtin_amdgcn_mfma_f32_16x16x32_f16(af[kk], b, acc[c2], 0, 0, 0);
            }
        }
        __syncthreads();   // everyone done reading h before it becomes Cs
#pragma unroll
        for (int c2 = 0; c2 < 4; ++c2) {
            int col = wave * 64 + c2 * 16 + l15;
#pragma unroll
            for (int r = 0; r < 4; ++r) {
                int row = quad * 4 + r;
                h[row][col] = (_Float16)(acc[c2][r] * sdv[row]);
            }
        }
        __syncthreads();
        int row = tid >> 3, seg = tid & 7;
        int gm = n0 + row;
        *(half8*)(hout + (size_t)gm * 128 + seg * 16)     = *(const half8*)&h[row][seg * 16];
        *(half8*)(hout + (size_t)gm * 128 + seg * 16 + 8) = *(const half8*)&h[row][seg * 16 + 8];
    }
}

// ---------------- LAST layer: aggregate(3) | attention(3) | softmax-fuse | out-projection ----------
// Same P1/P2 as k_layer but: no hh[3] global write, no scores[3] round trip; fuse + out-proj done
// in-block (h3 already in LDS; hh[0..2] rows read coalesced; alpha per node from 3 global scores +
// the locally-computed s3). Deletes k_fuse_out and ~25.6 MB of hh[3] traffic.
__global__ __launch_bounds__(128) void k_layer_last(const _Float16* __restrict__ hin,
                                                    const int* __restrict__ cnt, const int* __restrict__ esrc,
                                                    const float* __restrict__ bias,
                                                    const _Float16* __restrict__ WTatt,
                                                    const float* __restrict__ a_att,
                                                    const float* __restrict__ scores,
                                                    const _Float16* __restrict__ h0g,
                                                    const _Float16* __restrict__ h1g,
                                                    const _Float16* __restrict__ h2g,
                                                    const _Float16* __restrict__ WoutT,
                                                    const float* __restrict__ bout,
                                                    float* __restrict__ out) {
    __shared__ __align__(16) _Float16 h[16][CSTR];
    __shared__ float bsh[128];
    __shared__ float pp[2][16];
    int tid = threadIdx.x;
    bsh[tid] = bias[tid];
    int wave = tid >> 6, lane = tid & 63;
    int n0 = blockIdx.x * 16;
    int nl = tid >> 3, cl = tid & 7, c16 = cl * 16;
    int n = n0 + nl;

    // ---- P1: aggregate (identical math to k_layer; h3 stays in LDS only) ----
    {
        int cv = cnt[n];
        int beg = n * WELL, end = beg + cv;
        float dn = rsqrtf((float)cv + 1.0f);
        const _Float16* sp = hin + (size_t)n * 128 + c16;
        half8 sv0 = *(const half8*)sp;
        half8 sv1 = *(const half8*)(sp + 8);

        float a[16];
#pragma unroll
        for (int u = 0; u < 16; ++u) a[u] = 0.f;

        int idxA[4]; float mskA[4];
#pragma unroll
        for (int i = 0; i < 4; ++i) {
            int ei = beg + i;
            int t = esrc[ei];
            bool ok = ei < end;
            idxA[i] = ok ? t : n;
            mskA[i] = ok ? 1.f : 0.f;
        }
        for (int e = beg; e < end; e += 4) {
            half8 v0[4], v1[4];
#pragma unroll
            for (int i = 0; i < 4; ++i) {
                const _Float16* p = hin + (size_t)idxA[i] * 128 + c16;
                v0[i] = *(const half8*)p;
                v1[i] = *(const half8*)(p + 8);
            }
            int idxB[4]; float mskB[4];
#pragma unroll
            for (int i = 0; i < 4; ++i) {
                int ei = e + 4 + i;
                int t = esrc[ei];
                bool ok = ei < end;
                idxB[i] = ok ? t : n;
                mskB[i] = ok ? 1.f : 0.f;
            }
#pragma unroll
            for (int i = 0; i < 4; ++i) {
                float m = mskA[i];
#pragma unroll
                for (int u = 0; u < 8; ++u) {
                    a[u]     += m * (float)v0[i][u];
                    a[8 + u] += m * (float)v1[i][u];
                }
            }
#pragma unroll
            for (int i = 0; i < 4; ++i) { idxA[i] = idxB[i]; mskA[i] = mskB[i]; }
        }
        __syncthreads();   // bsh ready
        half8 o0, o1;
#pragma unroll
        for (int u = 0; u < 8; ++u) {
            float r0 = (a[u]     + (float)sv0[u]) * dn + bsh[c16 + u];
            float r1 = (a[8 + u] + (float)sv1[u]) * dn + bsh[c16 + 8 + u];
            o0[u] = (_Float16)fmaxf(r0, 0.f);
            o1[u] = (_Float16)fmaxf(r1, 0.f);
        }
        *(half8*)&h[nl][c16]     = o0;
        *(half8*)&h[nl][c16 + 8] = o1;
    }
    __syncthreads();

    int quad = lane >> 4, l15 = lane & 15;
    int ko = quad * 8;

    // ---- P2: attention scores for layer 3 (kept in LDS pp; no global round trip) ----
    {
        half8 af[4];
#pragma unroll
        for (int kk = 0; kk < 4; ++kk) af[kk] = *(const half8*)&h[l15][kk * 32 + ko];
        float p[4] = {0.f, 0.f, 0.f, 0.f};
#pragma unroll
        for (int c2 = 0; c2 < 4; ++c2) {
            int ct = wave * 4 + c2;
            half8 b[4];
#pragma unroll
            for (int kk = 0; kk < 4; ++kk)
                b[kk] = *(const half8*)&WTatt[((kk * 8 + ct) * 64 + lane) * 8];
            floatx4 acc = (floatx4){0.f, 0.f, 0.f, 0.f};
#pragma unroll
            for (int kk = 0; kk < 4; ++kk)
                acc = __builtin_amdgcn_mfma_f32_16x16x32_f16(af[kk], b[kk], acc, 0, 0, 0);
            float av = a_att[ct * 16 + l15];
#pragma unroll
            for (int r = 0; r < 4; ++r) p[r] += av * fast_tanh(acc[r]);
        }
#pragma unroll
        for (int r = 0; r < 4; ++r) {
            float v = p[r];
            v += __shfl_xor(v, 1); v += __shfl_xor(v, 2);
            v += __shfl_xor(v, 4); v += __shfl_xor(v, 8);
            if (l15 == 0) pp[wave][quad * 4 + r] = v;
        }
    }
    __syncthreads();

    // ---- P4: per-node softmax over layers + fused = sum_l alpha_l h_l (lane owns 16 channels) ----
    {
        float s0 = scores[(size_t)n * 4 + 0];
        float s1 = scores[(size_t)n * 4 + 1];
        float s2 = scores[(size_t)n * 4 + 2];
        float s3 = pp[0][nl] + pp[1][nl];
        float mx = fmaxf(fmaxf(s0, s1), fmaxf(s2, s3));
        float e0 = __expf(s0 - mx), e1 = __expf(s1 - mx), e2 = __expf(s2 - mx), e3 = __expf(s3 - mx);
        float inv = 1.0f / (e0 + e1 + e2 + e3);
        float al0 = e0 * inv, al1 = e1 * inv, al2 = e2 * inv, al3 = e3 * inv;

        const _Float16* p0 = h0g + (size_t)n * 128 + c16;
        const _Float16* p1 = h1g + (size_t)n * 128 + c16;
        const _Float16* p2 = h2g + (size_t)n * 128 + c16;
        half8 a0 = *(const half8*)p0, b0 = *(const half8*)(p0 + 8);
        half8 a1 = *(const half8*)p1, b1 = *(const half8*)(p1 + 8);
        half8 a2 = *(const half8*)p2, b2 = *(const half8*)(p2 + 8);
        half8 a3 = *(const half8*)&h[nl][c16], b3 = *(const half8*)&h[nl][c16 + 8];
        half8 f0, f1;
#pragma unroll
        for (int u = 0; u < 8; ++u) {
            f0[u] = (_Float16)(al0 * (float)a0[u] + al1 * (float)a1[u] +
                               al2 * (float)a2[u] + al3 * (float)a3[u]);
            f1[u] = (_Float16)(al0 * (float)b0[u] + al1 * (float)b1[u] +
                               al2 * (float)b2[u] + al3 * (float)b3[u]);
        }
        __syncthreads();   // (each lane reads/writes only its own row slice, but keep phases clean)
        *(half8*)&h[nl][c16]     = f0;
        *(half8*)&h[nl][c16 + 8] = f1;
    }
    __syncthreads();

    // ---- P5: out-projection MFMA: wave0 -> col tiles 0,1; wave1 -> col tile 2 ----
    {
        half8 ff[4];
#pragma unroll
        for (int kk = 0; kk < 4; ++kk) ff[kk] = *(const half8*)&h[l15][kk * 32 + ko];
        int nct = (wave == 0) ? 2 : 1;
#pragma unroll
        for (int c2 = 0; c2 < 2; ++c2) {
            if (c2 >= nct) break;
            int ct = (wave == 0) ? c2 : 2;
            half8 bw[4];
#pragma unroll
            for (int kk = 0; kk < 4; ++kk)
                bw[kk] = *(const half8*)(WoutT + ((kk * 3 + ct) * 64 + lane) * 8);
            floatx4 acc = (floatx4){0.f, 0.f, 0.f, 0.f};
#pragma unroll
            for (int kk = 0; kk < 4; ++kk)
                acc = __builtin_amdgcn_mfma_f32_16x16x32_f16(ff[kk], bw[kk], acc, 0, 0, 0);
            int col = ct * 16 + l15;
            if (col < NCLASS) {
                float bv = bout[col];
#pragma unroll
                for (int r = 0; r < 4; ++r) {
                    int node = n0 + quad * 4 + r;
                    out[(size_t)node * NCLASS + col] = acc[r] + bv;
                }
            }
        }
    }
}

extern "C" void kernel_launch(void* const* d_in, const int* in_sizes, int n_in,
                              void* d_out, int out_size, void* d_ws, size_t ws_size,
                              hipStream_t stream) {
    const float* x     = (const float*)d_in[0];
    const int*   ei    = (const int*)d_in[1];
    const float* convW = (const float*)d_in[2];
    const float* convb = (const float*)d_in[3];
    const float* W_att = (const float*)d_in[4];
    const float* a_att = (const float*)d_in[5];
    const float* W_out = (const float*)d_in[6];
    const float* b_out = (const float*)d_in[7];
    float* out = (float*)d_out;

    char* ws = (char*)d_ws;
    size_t off = 0;
    auto take = [&](size_t nbytes) { char* p = ws + off; off += (nbytes + 255) & ~(size_t)255; return p; };
    int*          cnt     = (int*)take(NNODES * 4);
    int*          gbase   = (int*)take((size_t)NB * 32 * 4);                // padded bucket counters
    unsigned int* ebuf    = (unsigned int*)take((size_t)NB * BUCKCAP * 4);  // packed (doff<<16|src)
    int*          esrc    = (int*)take((size_t)NNODES * WELL * 4 + 1024);   // ELL
    _Float16*     WoutT   = (_Float16*)take((size_t)48 * 128 * 2);
    float*        scores  = (float*)take(NNODES * 4 * 4);
    _Float16*     WT      = (_Float16*)take((size_t)5 * 128 * 128 * 2);
    _Float16*     hWsA    = (_Float16*)take((size_t)NNODES * 128 * 2);
    _Float16*     hh[3];
    for (int l = 0; l < 3; ++l) hh[l] = (_Float16*)take((size_t)NNODES * 128 * 2);
    _Float16*     hWsB    = (_Float16*)take((size_t)NNODES * 128 * 2);

    const int* src = ei;
    const int* dst = ei + NEDGES;

    hipMemsetAsync(gbase, 0, (size_t)NB * 32 * 4, stream);
    k_part<<<EBLK + PREPB + WOUTB, 1024, 0, stream>>>(src, dst, gbase, ebuf, convW, W_att, WT, W_out, WoutT);
    k_build<<<NB, 1024, 0, stream>>>(gbase, ebuf, esrc, cnt);
    k_gemm0<<<GEMMB, 256, 0, stream>>>(x, WT, cnt, hWsA);

    // layers 0-2: aggregate(l) + attention(l) + gemm(l+1); hWs ping-pongs A->B->A->B
    k_layer<<<XBLK, 128, 0, stream>>>(hWsA, cnt, esrc, convb + 0 * 128, hh[0],
                                      WT + 4 * 16384, a_att, scores, 0, WT + 1 * 16384, hWsB);
    k_layer<<<XBLK, 128, 0, stream>>>(hWsB, cnt, esrc, convb + 1 * 128, hh[1],
                                      WT + 4 * 16384, a_att, scores, 1, WT + 2 * 16384, hWsA);
    k_layer<<<XBLK, 128, 0, stream>>>(hWsA, cnt, esrc, convb + 2 * 128, hh[2],
                                      WT + 4 * 16384, a_att, scores, 2, WT + 3 * 16384, hWsB);
    // layer 3 + softmax-fuse + out-projection, all in one kernel
    k_layer_last<<<XBLK, 128, 0, stream>>>(hWsB, cnt, esrc, convb + 3 * 128,
                                           WT + 4 * 16384, a_att, scores,
                                           hh[0], hh[1], hh[2], WoutT, b_out, out);
}

// Round 12
// 281.294 us; speedup vs baseline: 1.1722x; 1.0182x over previous
//
#include <hip/hip_runtime.h>

#define NNODES 50000
#define NEDGES 800000
#define NCLASS 40
#define GEMMB 782      // ceil(NNODES/64)
#define XBLK  3125     // NNODES/16, 16 nodes per 128-thread layer block
#define WELL  64       // ELL width (Poisson(16) max degree ~45; 64 = huge margin)

// ---- edge-partition geometry ----
#define EBLK  782      // edge blocks of 1024 threads (800K edges)
#define PREPB 80       // 5*16384/1024 weight-prep blocks
#define WOUTB 6        // 6144/1024 WoutT-prep blocks
#define BSHIFT 10
#define NB    49       // ceil(50000/1024) coarse buckets
#define BUCKCAP 20480  // per-bucket ebuf region (mean 16384, sd~127 -> +32 sigma)

typedef _Float16 half8  __attribute__((ext_vector_type(8)));
typedef float    floatx4 __attribute__((ext_vector_type(4)));

#define CSTR 136
#define SMEM_BYTES (64 * CSTR * 2 + 256)

__device__ __forceinline__ float fast_tanh(float x) {
    return 1.0f - 2.0f / (__expf(2.0f * x) + 1.0f);
}

// ---------------- phase A: single-pass bucket partition | weight prep (frag order) ----------------
// Per block: LDS histogram of 49 coarse buckets -> wave-scan -> bin packed edges into LDS in
// bucket order -> ONE global atomicAdd per (block,bucket) claims a disjoint range -> thread t
// writes stage[t] to consecutive global addresses (coalesced ~21-edge runs). This replaces the
// per-lane scattered 4B stores (64 scattered addresses per wave) of the previous version.
// Fragment layout (per 128x128 mat): element (n = ct*16 + l15, k = kk*32 + quad*8 + j)
// stored at ((kk*8 + ct)*64 + quad*16 + l15)*8 + j.
__global__ __launch_bounds__(1024) void k_part(const int* __restrict__ src, const int* __restrict__ dst,
                                               int* __restrict__ gbase, unsigned int* __restrict__ ebuf,
                                               const float* __restrict__ convW, const float* __restrict__ W_att,
                                               _Float16* __restrict__ WT,
                                               const float* __restrict__ Wout, _Float16* __restrict__ WoutT) {
    int bid = blockIdx.x, tid = threadIdx.x;
    if (bid < EBLK) {
        __shared__ int hist[NB];
        __shared__ int lofs[NB + 1];
        __shared__ int base[NB];
        __shared__ unsigned int stage[1024];
        if (tid < NB) hist[tid] = 0;
        __syncthreads();
        int e = bid * 1024 + tid;
        bool ok = e < NEDGES;
        int b = 0, slot = 0;
        unsigned int packed = 0;
        if (ok) {
            int d = dst[e];
            int s = src[e];
            b = d >> BSHIFT;
            slot = atomicAdd(&hist[b], 1);
            packed = ((unsigned int)(d & ((1 << BSHIFT) - 1)) << 16) | (unsigned int)s;
        }
        __syncthreads();
        // exclusive scan of hist (49 values) in wave 0; claim global bases
        if (tid < 64) {
            int v = (tid < NB) ? hist[tid] : 0;
            int inc = v;
#pragma unroll
            for (int d2 = 1; d2 < 64; d2 <<= 1) {
                int o = __shfl_up(inc, d2);
                if (tid >= d2) inc += o;
            }
            if (tid < NB) lofs[tid] = inc - v;
            if (tid == NB - 1) lofs[NB] = inc;   // total valid edges in block
        }
        if (tid < NB) base[tid] = atomicAdd(&gbase[tid * 32], hist[tid]);   // padded counters: 1/line
        __syncthreads();
        if (ok) stage[lofs[b] + slot] = packed;
        __syncthreads();
        int total = lofs[NB];
        if (tid < total) {
            // find bucket of position tid: largest bb with lofs[bb] <= tid
            int lo = 0, hi = NB;
            while (hi - lo > 1) { int mid = (lo + hi) >> 1; if (lofs[mid] <= tid) lo = mid; else hi = mid; }
            int pos = base[lo] + (tid - lofs[lo]);
            if (pos < BUCKCAP) ebuf[(size_t)lo * BUCKCAP + pos] = stage[tid];   // clamp: ~32-sigma guard
        }
    } else if (bid < EBLK + PREPB) {
        int idx = (bid - EBLK) * 1024 + tid;   // < 5*16384
        int mat = idx >> 14, rem = idx & 16383;
        int j = rem & 7, lane = (rem >> 3) & 63, tile = rem >> 9;
        int l15 = lane & 15, quad = lane >> 4;
        int ct = tile & 7, kk = tile >> 3;
        int n = ct * 16 + l15, k = kk * 32 + quad * 8 + j;
        const float* s = (mat < 4) ? (convW + mat * 16384) : W_att;
        WT[idx] = (_Float16)s[k * 128 + n];
    } else {
        int idx = (bid - EBLK - PREPB) * 1024 + tid;   // < 6144
        int j = idx & 7, lane = (idx >> 3) & 63, tile = idx >> 9;
        int l15 = lane & 15, quad = lane >> 4;
        int ct = tile % 3, kk = tile / 3;
        int n = ct * 16 + l15, k = kk * 32 + quad * 8 + j;
        WoutT[idx] = (n < NCLASS) ? (_Float16)Wout[k * NCLASS + n] : (_Float16)0.f;
    }
}

// ---------------- phase B: per-bucket-quarter ELL build (4 blocks/bucket = 196 blocks) -------------
// Each block owns 256 nodes (quarter bucket): scans the whole bucket's edges (coalesced, L2-warm;
// 4x read amplification is ~2us), filters to its quarter, LDS-counts 256 nodes, writes esrc into
// a 64KB L2-resident window.
__global__ __launch_bounds__(1024) void k_build(const int* __restrict__ gbase,
                                                const unsigned int* __restrict__ ebuf,
                                                int* __restrict__ esrc, int* __restrict__ cnt) {
    __shared__ int lcnt[256];
    int b = blockIdx.x >> 2, q = blockIdx.x & 3;
    int t = threadIdx.x;
    if (t < 256) lcnt[t] = 0;
    __syncthreads();
    int n0 = b << BSHIFT;
    int total = gbase[b * 32];
    if (total > BUCKCAP) total = BUCKCAP;          // clamp (mirror of k_part guard)
    const unsigned int* ep = ebuf + (size_t)b * BUCKCAP;
    for (int i = t; i < total; i += 1024) {
        unsigned int p = ep[i];
        int doff = (int)(p >> 16);
        if ((doff >> 8) == q) {
            int slot = atomicAdd(&lcnt[doff & 255], 1);
            if (slot < WELL) esrc[(n0 + doff) * WELL + slot] = (int)(p & 0xFFFFu);   // degree>64 ~1e-17
        }
    }
    __syncthreads();
    if (t < 256) {
        int n = n0 + (q << 8) + t;
        if (n < NNODES) cnt[n] = (lcnt[t] < WELL) ? lcnt[t] : WELL;
    }
}

// ---------------- 64-row GEMM (layer-0 only, fp32 A): C = (A @ W) * dinv; dinv from cnt ------------
__global__ __launch_bounds__(256) void k_gemm0(const float* __restrict__ Av, const _Float16* __restrict__ WTf,
                                               const int* __restrict__ cnt, _Float16* __restrict__ C) {
    __shared__ __align__(16) char smem[SMEM_BYTES];
    _Float16 (*Csh)[CSTR] = (_Float16 (*)[CSTR])smem;
    float* sdinv = (float*)(smem + 64 * CSTR * 2);
    int m0 = blockIdx.x * 64;
    int tid = threadIdx.x;
    int wave = tid >> 6, lane = tid & 63;
    int quad = lane >> 4, l15 = lane & 15;
    int ko = quad * 8;

    if (tid < 64) {
        int r = m0 + tid; if (r > NNODES - 1) r = NNODES - 1;
        sdinv[tid] = rsqrtf((float)cnt[r] + 1.0f);
    }

    floatx4 acc[4][2];
#pragma unroll
    for (int rt = 0; rt < 4; ++rt)
#pragma unroll
        for (int ct = 0; ct < 2; ++ct) acc[rt][ct] = (floatx4){0.f, 0.f, 0.f, 0.f};

#pragma unroll
    for (int kk = 0; kk < 4; ++kk) {
        half8 a[4], b[2];
#pragma unroll
        for (int rt = 0; rt < 4; ++rt) {
            int row = m0 + rt * 16 + l15;
            if (row > NNODES - 1) row = NNODES - 1;
            const float* Ap = Av + (size_t)row * 128 + kk * 32 + ko;
            float4 f0 = *(const float4*)Ap;
            float4 f1 = *(const float4*)(Ap + 4);
            a[rt] = (half8){(_Float16)f0.x, (_Float16)f0.y, (_Float16)f0.z, (_Float16)f0.w,
                            (_Float16)f1.x, (_Float16)f1.y, (_Float16)f1.z, (_Float16)f1.w};
        }
#pragma unroll
        for (int ct = 0; ct < 2; ++ct)
            b[ct] = *(const half8*)&WTf[((kk * 8 + (wave * 2 + ct)) * 64 + lane) * 8];
#pragma unroll
        for (int rt = 0; rt < 4; ++rt)
#pragma unroll
            for (int ct = 0; ct < 2; ++ct)
                acc[rt][ct] = __builtin_amdgcn_mfma_f32_16x16x32_f16(a[rt], b[ct], acc[rt][ct], 0, 0, 0);
    }
    __syncthreads();   // sdinv visible

#pragma unroll
    for (int rt = 0; rt < 4; ++rt)
#pragma unroll
        for (int r = 0; r < 4; ++r) {
            float d = sdinv[rt * 16 + quad * 4 + r];
#pragma unroll
            for (int ct = 0; ct < 2; ++ct)
                Csh[rt * 16 + quad * 4 + r][wave * 32 + ct * 16 + l15] = (_Float16)(acc[rt][ct][r] * d);
        }
    __syncthreads();

    int row = tid >> 2, seg = tid & 3;
    int gm = m0 + row;
    if (gm < NNODES) {
#pragma unroll
        for (int j = 0; j < 4; ++j)
            *(half8*)(C + (size_t)gm * 128 + seg * 32 + j * 8) = *(const half8*)&Csh[row][seg * 32 + j * 8];
    }
}

// ---------------- fused layer kernel (layers 0-2): aggregate(l) | attention(l) | gemm(l+1) --------
// Block = 128 threads (2 waves), 16 nodes. Aggregation: 8 lanes/node, 4-deep pipelined gathers.
// ELL edge list: beg = n*WELL, end = beg + cnt[n]. Post-relu h kept in LDS -> attention and
// next-layer GEMM read it from LDS. Gathers read hin; gemm writes hout (ping-pong, no race).
__global__ __launch_bounds__(128) void k_layer(const _Float16* __restrict__ hin,
                                               const int* __restrict__ cnt, const int* __restrict__ esrc,
                                               const float* __restrict__ bias,
                                               _Float16* __restrict__ hh,
                                               const _Float16* __restrict__ WTatt, const float* __restrict__ a_att,
                                               float* __restrict__ scores, int layer,
                                               const _Float16* __restrict__ WTnext, _Float16* __restrict__ hout) {
    __shared__ __align__(16) _Float16 h[16][CSTR];   // 4,352 B; reused as Cs in the gemm epilogue
    __shared__ float bsh[128];
    __shared__ float sdv[16];
    __shared__ float pp[2][16];
    int tid = threadIdx.x;
    bsh[tid] = bias[tid];
    int wave = tid >> 6, lane = tid & 63;
    int n0 = blockIdx.x * 16;

    // ---- P1: aggregate 16 nodes (8 lanes per node, 16 channels per lane) ----
    {
        int nl = tid >> 3;               // 0..15
        int cl = tid & 7;
        int c16 = cl * 16;
        int n = n0 + nl;                 // XBLK*16 == NNODES: always valid
        int cv = cnt[n];
        int beg = n * WELL, end = beg + cv;
        float dn = rsqrtf((float)cv + 1.0f);
        const _Float16* sp = hin + (size_t)n * 128 + c16;
        half8 sv0 = *(const half8*)sp;
        half8 sv1 = *(const half8*)(sp + 8);

        float a[16];
#pragma unroll
        for (int u = 0; u < 16; ++u) a[u] = 0.f;

        int idxA[4]; float mskA[4];
#pragma unroll
        for (int i = 0; i < 4; ++i) {
            int ei = beg + i;
            int t = esrc[ei];            // within the 64-slot row: always in-bounds
            bool ok = ei < end;
            idxA[i] = ok ? t : n;
            mskA[i] = ok ? 1.f : 0.f;
        }
        for (int e = beg; e < end; e += 4) {
            half8 v0[4], v1[4];
#pragma unroll
            for (int i = 0; i < 4; ++i) {
                const _Float16* p = hin + (size_t)idxA[i] * 128 + c16;
                v0[i] = *(const half8*)p;
                v1[i] = *(const half8*)(p + 8);
            }
            int idxB[4]; float mskB[4];
#pragma unroll
            for (int i = 0; i < 4; ++i) {
                int ei = e + 4 + i;
                int t = esrc[ei];        // within row (cv+8 <= 53 < 64)
                bool ok = ei < end;
                idxB[i] = ok ? t : n;
                mskB[i] = ok ? 1.f : 0.f;
            }
#pragma unroll
            for (int i = 0; i < 4; ++i) {
                float m = mskA[i];
#pragma unroll
                for (int u = 0; u < 8; ++u) {
                    a[u]     += m * (float)v0[i][u];
                    a[8 + u] += m * (float)v1[i][u];
                }
            }
#pragma unroll
            for (int i = 0; i < 4; ++i) { idxA[i] = idxB[i]; mskA[i] = mskB[i]; }
        }
        __syncthreads();   // bsh ready
        half8 o0, o1;
#pragma unroll
        for (int u = 0; u < 8; ++u) {
            float r0 = (a[u]     + (float)sv0[u]) * dn + bsh[c16 + u];
            float r1 = (a[8 + u] + (float)sv1[u]) * dn + bsh[c16 + 8 + u];
            o0[u] = (_Float16)fmaxf(r0, 0.f);
            o1[u] = (_Float16)fmaxf(r1, 0.f);
        }
        *(half8*)(hh + (size_t)n * 128 + c16)     = o0;
        *(half8*)(hh + (size_t)n * 128 + c16 + 8) = o1;
        *(half8*)&h[nl][c16]     = o0;
        *(half8*)&h[nl][c16 + 8] = o1;
        if (cl == 0) sdv[nl] = dn;
    }
    __syncthreads();

    int quad = lane >> 4, l15 = lane & 15;
    int ko = quad * 8;
    half8 af[4];                          // A-frags of the 16 rows, shared by attn + gemm
#pragma unroll
    for (int kk = 0; kk < 4; ++kk) af[kk] = *(const half8*)&h[l15][kk * 32 + ko];

    // ---- P2: attention scores for these 16 nodes (wave w handles cols w*64..w*64+63) ----
    {
        float p[4] = {0.f, 0.f, 0.f, 0.f};
#pragma unroll
        for (int c2 = 0; c2 < 4; ++c2) {
            int ct = wave * 4 + c2;
            half8 b[4];
#pragma unroll
            for (int kk = 0; kk < 4; ++kk)
                b[kk] = *(const half8*)&WTatt[((kk * 8 + ct) * 64 + lane) * 8];
            floatx4 acc = (floatx4){0.f, 0.f, 0.f, 0.f};
#pragma unroll
            for (int kk = 0; kk < 4; ++kk)
                acc = __builtin_amdgcn_mfma_f32_16x16x32_f16(af[kk], b[kk], acc, 0, 0, 0);
            float av = a_att[ct * 16 + l15];
#pragma unroll
            for (int r = 0; r < 4; ++r) p[r] += av * fast_tanh(acc[r]);
        }
#pragma unroll
        for (int r = 0; r < 4; ++r) {
            float v = p[r];
            v += __shfl_xor(v, 1); v += __shfl_xor(v, 2);
            v += __shfl_xor(v, 4); v += __shfl_xor(v, 8);
            if (l15 == 0) pp[wave][quad * 4 + r] = v;
        }
    }
    __syncthreads();
    if (tid < 16) scores[(size_t)(n0 + tid) * 4 + layer] = pp[0][tid] + pp[1][tid];

    // ---- P3: next-layer GEMM, A from LDS ----
    {
        floatx4 acc[4];
#pragma unroll
        for (int c2 = 0; c2 < 4; ++c2) acc[c2] = (floatx4){0.f, 0.f, 0.f, 0.f};
#pragma unroll
        for (int c2 = 0; c2 < 4; ++c2) {
            int ct = wave * 4 + c2;
#pragma unroll
            for (int kk = 0; kk < 4; ++kk) {
                half8 b = *(const half8*)&WTnext[((kk * 8 + ct) * 64 + lane) * 8];
                acc[c2] = __builtin_amdgcn_mfma_f32_16x16x32_f16(af[kk], b, acc[c2], 0, 0, 0);
            }
        }
        __syncthreads();   // everyone done reading h before it becomes Cs
#pragma unroll
        for (int c2 = 0; c2 < 4; ++c2) {
            int col = wave * 64 + c2 * 16 + l15;
#pragma unroll
            for (int r = 0; r < 4; ++r) {
                int row = quad * 4 + r;
                h[row][col] = (_Float16)(acc[c2][r] * sdv[row]);
            }
        }
        __syncthreads();
        int row = tid >> 3, seg = tid & 7;
        int gm = n0 + row;
        *(half8*)(hout + (size_t)gm * 128 + seg * 16)     = *(const half8*)&h[row][seg * 16];
        *(half8*)(hout + (size_t)gm * 128 + seg * 16 + 8) = *(const half8*)&h[row][seg * 16 + 8];
    }
}

// ---------------- LAST layer: aggregate(3) | attention(3) | softmax-fuse | out-projection ----------
// Same P1/P2 as k_layer but: no hh[3] global write, no scores[3] round trip; fuse + out-proj done
// in-block (h3 already in LDS; hh[0..2] rows read coalesced; alpha per node from 3 global scores +
// the locally-computed s3). Deletes k_fuse_out and ~25.6 MB of hh[3] traffic.
__global__ __launch_bounds__(128) void k_layer_last(const _Float16* __restrict__ hin,
                                                    const int* __restrict__ cnt, const int* __restrict__ esrc,
                                                    const float* __restrict__ bias,
                                                    const _Float16* __restrict__ WTatt,
                                                    const float* __restrict__ a_att,
                                                    const float* __restrict__ scores,
                                                    const _Float16* __restrict__ h0g,
                                                    const _Float16* __restrict__ h1g,
                                                    const _Float16* __restrict__ h2g,
                                                    const _Float16* __restrict__ WoutT,
                                                    const float* __restrict__ bout,
                                                    float* __restrict__ out) {
    __shared__ __align__(16) _Float16 h[16][CSTR];
    __shared__ float bsh[128];
    __shared__ float pp[2][16];
    int tid = threadIdx.x;
    bsh[tid] = bias[tid];
    int wave = tid >> 6, lane = tid & 63;
    int n0 = blockIdx.x * 16;
    int nl = tid >> 3, cl = tid & 7, c16 = cl * 8 * 2;
    int n = n0 + nl;

    // ---- P1: aggregate (identical math to k_layer; h3 stays in LDS only) ----
    {
        int cv = cnt[n];
        int beg = n * WELL, end = beg + cv;
        float dn = rsqrtf((float)cv + 1.0f);
        const _Float16* sp = hin + (size_t)n * 128 + c16;
        half8 sv0 = *(const half8*)sp;
        half8 sv1 = *(const half8*)(sp + 8);

        float a[16];
#pragma unroll
        for (int u = 0; u < 16; ++u) a[u] = 0.f;

        int idxA[4]; float mskA[4];
#pragma unroll
        for (int i = 0; i < 4; ++i) {
            int ei = beg + i;
            int t = esrc[ei];
            bool ok = ei < end;
            idxA[i] = ok ? t : n;
            mskA[i] = ok ? 1.f : 0.f;
        }
        for (int e = beg; e < end; e += 4) {
            half8 v0[4], v1[4];
#pragma unroll
            for (int i = 0; i < 4; ++i) {
                const _Float16* p = hin + (size_t)idxA[i] * 128 + c16;
                v0[i] = *(const half8*)p;
                v1[i] = *(const half8*)(p + 8);
            }
            int idxB[4]; float mskB[4];
#pragma unroll
            for (int i = 0; i < 4; ++i) {
                int ei = e + 4 + i;
                int t = esrc[ei];
                bool ok = ei < end;
                idxB[i] = ok ? t : n;
                mskB[i] = ok ? 1.f : 0.f;
            }
#pragma unroll
            for (int i = 0; i < 4; ++i) {
                float m = mskA[i];
#pragma unroll
                for (int u = 0; u < 8; ++u) {
                    a[u]     += m * (float)v0[i][u];
                    a[8 + u] += m * (float)v1[i][u];
                }
            }
#pragma unroll
            for (int i = 0; i < 4; ++i) { idxA[i] = idxB[i]; mskA[i] = mskB[i]; }
        }
        __syncthreads();   // bsh ready
        half8 o0, o1;
#pragma unroll
        for (int u = 0; u < 8; ++u) {
            float r0 = (a[u]     + (float)sv0[u]) * dn + bsh[c16 + u];
            float r1 = (a[8 + u] + (float)sv1[u]) * dn + bsh[c16 + 8 + u];
            o0[u] = (_Float16)fmaxf(r0, 0.f);
            o1[u] = (_Float16)fmaxf(r1, 0.f);
        }
        *(half8*)&h[nl][c16]     = o0;
        *(half8*)&h[nl][c16 + 8] = o1;
    }
    __syncthreads();

    int quad = lane >> 4, l15 = lane & 15;
    int ko = quad * 8;

    // ---- P2: attention scores for layer 3 (kept in LDS pp; no global round trip) ----
    {
        half8 af[4];
#pragma unroll
        for (int kk = 0; kk < 4; ++kk) af[kk] = *(const half8*)&h[l15][kk * 32 + ko];
        float p[4] = {0.f, 0.f, 0.f, 0.f};
#pragma unroll
        for (int c2 = 0; c2 < 4; ++c2) {
            int ct = wave * 4 + c2;
            half8 b[4];
#pragma unroll
            for (int kk = 0; kk < 4; ++kk)
                b[kk] = *(const half8*)&WTatt[((kk * 8 + ct) * 64 + lane) * 8];
            floatx4 acc = (floatx4){0.f, 0.f, 0.f, 0.f};
#pragma unroll
            for (int kk = 0; kk < 4; ++kk)
                acc = __builtin_amdgcn_mfma_f32_16x16x32_f16(af[kk], b[kk], acc, 0, 0, 0);
            float av = a_att[ct * 16 + l15];
#pragma unroll
            for (int r = 0; r < 4; ++r) p[r] += av * fast_tanh(acc[r]);
        }
#pragma unroll
        for (int r = 0; r < 4; ++r) {
            float v = p[r];
            v += __shfl_xor(v, 1); v += __shfl_xor(v, 2);
            v += __shfl_xor(v, 4); v += __shfl_xor(v, 8);
            if (l15 == 0) pp[wave][quad * 4 + r] = v;
        }
    }
    __syncthreads();

    // ---- P4: per-node softmax over layers + fused = sum_l alpha_l h_l (lane owns 16 channels) ----
    {
        float s0 = scores[(size_t)n * 4 + 0];
        float s1 = scores[(size_t)n * 4 + 1];
        float s2 = scores[(size_t)n * 4 + 2];
        float s3 = pp[0][nl] + pp[1][nl];
        float mx = fmaxf(fmaxf(s0, s1), fmaxf(s2, s3));
        float e0 = __expf(s0 - mx), e1 = __expf(s1 - mx), e2 = __expf(s2 - mx), e3 = __expf(s3 - mx);
        float inv = 1.0f / (e0 + e1 + e2 + e3);
        float al0 = e0 * inv, al1 = e1 * inv, al2 = e2 * inv, al3 = e3 * inv;

        const _Float16* p0 = h0g + (size_t)n * 128 + c16;
        const _Float16* p1 = h1g + (size_t)n * 128 + c16;
        const _Float16* p2 = h2g + (size_t)n * 128 + c16;
        half8 a0 = *(const half8*)p0, b0 = *(const half8*)(p0 + 8);
        half8 a1 = *(const half8*)p1, b1 = *(const half8*)(p1 + 8);
        half8 a2 = *(const half8*)p2, b2 = *(const half8*)(p2 + 8);
        half8 a3 = *(const half8*)&h[nl][c16], b3 = *(const half8*)&h[nl][c16 + 8];
        half8 f0, f1;
#pragma unroll
        for (int u = 0; u < 8; ++u) {
            f0[u] = (_Float16)(al0 * (float)a0[u] + al1 * (float)a1[u] +
                               al2 * (float)a2[u] + al3 * (float)a3[u]);
            f1[u] = (_Float16)(al0 * (float)b0[u] + al1 * (float)b1[u] +
                               al2 * (float)b2[u] + al3 * (float)b3[u]);
        }
        __syncthreads();   // (each lane reads/writes only its own row slice, but keep phases clean)
        *(half8*)&h[nl][c16]     = f0;
        *(half8*)&h[nl][c16 + 8] = f1;
    }
    __syncthreads();

    // ---- P5: out-projection MFMA: wave0 -> col tiles 0,1; wave1 -> col tile 2 ----
    {
        half8 ff[4];
#pragma unroll
        for (int kk = 0; kk < 4; ++kk) ff[kk] = *(const half8*)&h[l15][kk * 32 + ko];
        int nct = (wave == 0) ? 2 : 1;
#pragma unroll
        for (int c2 = 0; c2 < 2; ++c2) {
            if (c2 >= nct) break;
            int ct = (wave == 0) ? c2 : 2;
            half8 bw[4];
#pragma unroll
            for (int kk = 0; kk < 4; ++kk)
                bw[kk] = *(const half8*)(WoutT + ((kk * 3 + ct) * 64 + lane) * 8);
            floatx4 acc = (floatx4){0.f, 0.f, 0.f, 0.f};
#pragma unroll
            for (int kk = 0; kk < 4; ++kk)
                acc = __builtin_amdgcn_mfma_f32_16x16x32_f16(ff[kk], bw[kk], acc, 0, 0, 0);
            int col = ct * 16 + l15;
            if (col < NCLASS) {
                float bv = bout[col];
#pragma unroll
                for (int r = 0; r < 4; ++r) {
                    int node = n0 + quad * 4 + r;
                    out[(size_t)node * NCLASS + col] = acc[r] + bv;
                }
            }
        }
    }
}

extern "C" void kernel_launch(void* const* d_in, const int* in_sizes, int n_in,
                              void* d_out, int out_size, void* d_ws, size_t ws_size,
                              hipStream_t stream) {
    const float* x     = (const float*)d_in[0];
    const int*   ei    = (const int*)d_in[1];
    const float* convW = (const float*)d_in[2];
    const float* convb = (const float*)d_in[3];
    const float* W_att = (const float*)d_in[4];
    const float* a_att = (const float*)d_in[5];
    const float* W_out = (const float*)d_in[6];
    const float* b_out = (const float*)d_in[7];
    float* out = (float*)d_out;

    char* ws = (char*)d_ws;
    size_t off = 0;
    auto take = [&](size_t nbytes) { char* p = ws + off; off += (nbytes + 255) & ~(size_t)255; return p; };
    int*          cnt     = (int*)take(NNODES * 4);
    int*          gbase   = (int*)take((size_t)NB * 32 * 4);                // padded bucket counters
    unsigned int* ebuf    = (unsigned int*)take((size_t)NB * BUCKCAP * 4);  // packed (doff<<16|src)
    int*          esrc    = (int*)take((size_t)NNODES * WELL * 4 + 1024);   // ELL
    _Float16*     WoutT   = (_Float16*)take((size_t)48 * 128 * 2);
    float*        scores  = (float*)take(NNODES * 4 * 4);
    _Float16*     WT      = (_Float16*)take((size_t)5 * 128 * 128 * 2);
    _Float16*     hWsA    = (_Float16*)take((size_t)NNODES * 128 * 2);
    _Float16*     hh[3];
    for (int l = 0; l < 3; ++l) hh[l] = (_Float16*)take((size_t)NNODES * 128 * 2);
    _Float16*     hWsB    = (_Float16*)take((size_t)NNODES * 128 * 2);

    const int* src = ei;
    const int* dst = ei + NEDGES;

    hipMemsetAsync(gbase, 0, (size_t)NB * 32 * 4, stream);
    k_part<<<EBLK + PREPB + WOUTB, 1024, 0, stream>>>(src, dst, gbase, ebuf, convW, W_att, WT, W_out, WoutT);
    k_build<<<NB * 4, 1024, 0, stream>>>(gbase, ebuf, esrc, cnt);
    k_gemm0<<<GEMMB, 256, 0, stream>>>(x, WT, cnt, hWsA);

    // layers 0-2: aggregate(l) + attention(l) + gemm(l+1); hWs ping-pongs A->B->A->B
    k_layer<<<XBLK, 128, 0, stream>>>(hWsA, cnt, esrc, convb + 0 * 128, hh[0],
                                      WT + 4 * 16384, a_att, scores, 0, WT + 1 * 16384, hWsB);
    k_layer<<<XBLK, 128, 0, stream>>>(hWsB, cnt, esrc, convb + 1 * 128, hh[1],
                                      WT + 4 * 16384, a_att, scores, 1, WT + 2 * 16384, hWsA);
    k_layer<<<XBLK, 128, 0, stream>>>(hWsA, cnt, esrc, convb + 2 * 128, hh[2],
                                      WT + 4 * 16384, a_att, scores, 2, WT + 3 * 16384, hWsB);
    // layer 3 + softmax-fuse + out-projection, all in one kernel
    k_layer_last<<<XBLK, 128, 0, stream>>>(hWsB, cnt, esrc, convb + 3 * 128,
                                           WT + 4 * 16384, a_att, scores,
                                           hh[0], hh[1], hh[2], WoutT, b_out, out);
}